// Round 12
// baseline (390.575 us; speedup 1.0000x reference)
//
#include <hip/hip_runtime.h>

typedef unsigned short u16;
typedef __attribute__((ext_vector_type(8))) short short8;
typedef __attribute__((ext_vector_type(4))) float float4v;

#define SCL2 (0.125f * 1.44269504088896340736f)   // logit scale folded into log2 domain
#define NEG_BIG -1.0e8f

// 16-lane rotation on the VALU pipe (DPP row_ror) — replaces shfl_xor (DS pipe)
#define ROR16(x, N) __int_as_float(__builtin_amdgcn_mov_dpp( \
    __float_as_int(x), 0x120 + (N), 0xF, 0xF, true))

static __device__ __forceinline__ u16 f2bf(float f) {
  union { float f; unsigned u; } x; x.f = f;
  unsigned r = x.u + 0x7fffu + ((x.u >> 16) & 1u);
  return (u16)(r >> 16);
}
static __device__ __forceinline__ float bf2f(u16 b) {
  union { unsigned u; float f; } x; x.u = ((unsigned)b) << 16;
  return x.f;
}
static __device__ __forceinline__ u16 f2h(float f) {
  union { u16 u; _Float16 h; } x; x.h = (_Float16)f; return x.u;
}

// ---------------------------------------------------------------------------
__global__ void detect_dtype(const unsigned* __restrict__ in0, int* __restrict__ flag) {
  if (threadIdx.x == 0 && blockIdx.x == 0) {
    int cnt = 0;
    for (int i = 0; i < 256; ++i) {
      unsigned e = (in0[i] >> 7) & 0xFFu;
      if (e >= 100u && e <= 140u) cnt++;
    }
    flag[0] = (cnt < 128) ? 1 : 0;
  }
}

// ---------------------------------------------------------------------------
// Merged prep: converts (input/memory/pose -> bf16) + 4 weight transposes in
// ONE dispatch (block-range table, all branches block-uniform).
// ---------------------------------------------------------------------------
__global__ __launch_bounds__(256) void prep_all(
    const void* __restrict__ A0, const void* __restrict__ A1, const void* __restrict__ A2,
    u16* __restrict__ O0, u16* __restrict__ O1, u16* __restrict__ O2,
    const void* __restrict__ W0, const void* __restrict__ W1,
    const void* __restrict__ W2, const void* __restrict__ W3,
    u16* __restrict__ T0, u16* __restrict__ T1,
    u16* __restrict__ T2, u16* __restrict__ T3,
    const int* __restrict__ dflag) {
  __shared__ __align__(16) u16 t[32][33];
  const int bid = blockIdx.x, tid = threadIdx.x;
  const int f32 = dflag[0];

  if (bid < 10240) {  // ---- converts ----
    int z = (bid < 4096) ? 0 : (bid < 8192) ? 1 : 2;
    int lb = bid - ((z == 0) ? 0 : (z == 1) ? 4096 : 8192);
    const void* in = (z == 0) ? A0 : (z == 1) ? A1 : A2;
    u16* out = (z == 0) ? O0 : (z == 1) ? O1 : O2;
    int i = (lb * 256 + tid) * 4;
    if (f32) {
      float4 v = *(const float4*)((const float*)in + i);
      u16 o[4] = {f2bf(v.x), f2bf(v.y), f2bf(v.z), f2bf(v.w)};
      *(uint2*)(out + i) = *(uint2*)o;
    } else {
      *(uint2*)(out + i) = *(const uint2*)((const u16*)in + i);
    }
    return;
  }
  // ---- transposes ----
  int z, lb;
  if (bid < 12288)      { z = 0; lb = bid - 10240; }
  else if (bid < 13312) { z = 1; lb = bid - 12288; }
  else if (bid < 14336) { z = 2; lb = bid - 13312; }
  else                  { z = 3; lb = bid - 14336; }
  const void* in = (z == 0) ? W0 : (z == 1) ? W1 : (z == 2) ? W2 : W3;
  u16* out = (z == 0) ? T0 : (z == 1) ? T1 : (z == 2) ? T2 : T3;
  const int C = (z == 0) ? 2048 : 1024;
  const int nbx = C / 32;
  const int bx = lb % nbx, by = lb / nbx;
  const int tx = tid & 31, ty = tid >> 5;            // 32x8
  int c = bx * 32 + tx;
  int rbase = by * 32;
#pragma unroll
  for (int k = 0; k < 4; ++k) {
    int r = rbase + ty + k * 8;
    size_t idx = (size_t)r * C + c;
    t[ty + k * 8][tx] = f32 ? f2bf(((const float*)in)[idx]) : ((const u16*)in)[idx];
  }
  __syncthreads();
  int r2 = rbase + tx;
#pragma unroll
  for (int k = 0; k < 4; ++k) {
    int c2 = bx * 32 + ty + k * 8;
    out[(size_t)c2 * 1024 + r2] = t[tx][ty + k * 8];
  }
}

// row pointer for A (or gathered [gmem;ginp] concat when A==nullptr)
static __device__ __forceinline__ const u16* gemm_arow(
    const u16* A, const u16* gmem, const u16* ginp,
    int lda, long aOff, long aZ, int z, int rg) {
  if (A) return A + (size_t)rg * lda + aOff + (long)z * aZ;
  int bb = rg >> 11, t = rg & 2047;
  return (t < 1024) ? (gmem + ((size_t)(bb * 1024 + t)) * 1024)
                    : (ginp + ((size_t)(bb * 1024 + t - 1024)) * 1024);
}

// ---------------------------------------------------------------------------
// Merged projection GEMM: kv + q + p in ONE dispatch (1408 blocks).
// Round-12: K is now ALSO written in fragment-contiguous layout (K4), like V4,
// so attn reads QK B-fragments straight from global (removes Ks LDS entirely):
//   K4[(((b*16+h)*16 + jt)*16 + kk*8 + nj)*64 + quad*16 + l15]*8 + i
//   where j = jt*128 + nj*16 + l15,  d = kk*32 + quad*8 + i   (bf16)
// Reader lane address = fragbase + lane*16B -> one coalesced 1KB load/frag.
// V4 layout: V4[(((b*16+h)*16+jt)*16+f)*64+lane][i] (fp16), unchanged.
// ---------------------------------------------------------------------------
__global__ __launch_bounds__(256) void gemm_proj(
    const u16* __restrict__ memB, const u16* __restrict__ inpB,
    const u16* __restrict__ poseB,
    const u16* __restrict__ WkvT, const u16* __restrict__ WqT,
    const u16* __restrict__ WpT,
    u16* __restrict__ Kb, u16* __restrict__ VT,
    u16* __restrict__ QU, u16* __restrict__ QV, u16* __restrict__ Pb,
    const void* __restrict__ ub, const void* __restrict__ vb,
    const int* __restrict__ dflag, int K)
{
  __shared__ __align__(16) u16 As[2][128][40];
  __shared__ __align__(16) u16 Bs[2][128][40];
  const int f32g = dflag[0];
  const int tid = threadIdx.x;
  const int w = tid >> 6, lane = tid & 63, quad = lane >> 4, l15 = lane & 15;
  const int wr = w >> 1, wc = w & 1;
  const int srow = tid >> 2, sc8 = (tid & 3) * 8;

  const int bid = blockIdx.x;
  int prob, bx, by;
  if (bid < 1024)      { prob = 0; bx = bid & 15; by = bid >> 4; }
  else if (bid < 1280) { int t = bid - 1024; prob = 1; bx = t & 7; by = t >> 3; }
  else                 { int t = bid - 1280; prob = 2; bx = t & 7; by = t >> 3; }
  const int m0 = by * 128, n0 = bx * 128;
  const u16* BT = (prob == 0) ? WkvT : (prob == 1) ? WqT : WpT;

  const u16 *apr0, *apr1;
  if (prob == 0) {
    apr0 = gemm_arow(nullptr, memB, inpB, 0, 0, 0, 0, m0 + srow) + sc8;
    apr1 = gemm_arow(nullptr, memB, inpB, 0, 0, 0, 0, m0 + 64 + srow) + sc8;
  } else {
    const u16* Ab = (prob == 1) ? inpB : poseB;
    apr0 = Ab + (size_t)(m0 + srow) * 1024 + sc8;
    apr1 = Ab + (size_t)(m0 + 64 + srow) * 1024 + sc8;
  }
  const u16* bpr0 = BT + (size_t)(n0 + srow) * 1024 + sc8;
  const u16* bpr1 = BT + (size_t)(n0 + 64 + srow) * 1024 + sc8;

  float4v acc[4][4];
#pragma unroll
  for (int i = 0; i < 4; ++i)
#pragma unroll
    for (int j = 0; j < 4; ++j) acc[i][j] = (float4v){0.f, 0.f, 0.f, 0.f};

  uint4 aR0 = *(const uint4*)(apr0);
  uint4 aR1 = *(const uint4*)(apr1);
  uint4 bR0 = *(const uint4*)(bpr0);
  uint4 bR1 = *(const uint4*)(bpr1);

  int p = 0;
  for (int kt = 0; kt < K; kt += 32, p ^= 1) {
    *(uint4*)&As[p][srow][sc8] = aR0;
    *(uint4*)&As[p][64 + srow][sc8] = aR1;
    *(uint4*)&Bs[p][srow][sc8] = bR0;
    *(uint4*)&Bs[p][64 + srow][sc8] = bR1;
    __syncthreads();
    if (kt + 32 < K) {
      aR0 = *(const uint4*)(apr0 + kt + 32);
      aR1 = *(const uint4*)(apr1 + kt + 32);
      bR0 = *(const uint4*)(bpr0 + kt + 32);
      bR1 = *(const uint4*)(bpr1 + kt + 32);
    }
    short8 af[4], bf[4];
#pragma unroll
    for (int mi = 0; mi < 4; ++mi)
      af[mi] = *(const short8*)&As[p][wr * 64 + mi * 16 + l15][quad * 8];
#pragma unroll
    for (int ni = 0; ni < 4; ++ni)
      bf[ni] = *(const short8*)&Bs[p][wc * 64 + ni * 16 + l15][quad * 8];
#pragma unroll
    for (int mi = 0; mi < 4; ++mi)
#pragma unroll
      for (int ni = 0; ni < 4; ++ni)
        acc[mi][ni] = __builtin_amdgcn_mfma_f32_16x16x32_bf16(af[mi], bf[ni], acc[mi][ni], 0, 0, 0);
    // single barrier per K-step: next iter writes the OTHER buffer
  }

#pragma unroll
  for (int mi = 0; mi < 4; ++mi) {
#pragma unroll
    for (int ni = 0; ni < 4; ++ni) {
      int rg0 = m0 + wr * 64 + mi * 16 + quad * 4;
      int cg = n0 + wc * 64 + ni * 16 + l15;
      if (prob == 0) {
        int bb = rg0 >> 11, t0 = rg0 & 2047;
        int jt = t0 >> 7, tp = t0 & 127;
        if (cg >= 1024) {   // V -> fragment-contiguous V4 layout (fp16)
          int d_full = cg - 1024;
          int hh = d_full >> 6, dd = d_full & 63;
          int niv = dd >> 4, lv = dd & 15;
          int f = ((tp >> 5) << 2) + niv;
          int lanev = ((tp >> 3) & 3) * 16 + lv;
          int iv = tp & 7;
          size_t Aidx = ((((size_t)(bb * 16 + hh) * 16 + jt) * 16 + f) * 64 + lanev) * 8 + iv;
          u16 h4[4] = {f2h(acc[mi][ni][0]), f2h(acc[mi][ni][1]),
                       f2h(acc[mi][ni][2]), f2h(acc[mi][ni][3])};
          *(uint2*)&VT[Aidx] = *(uint2*)h4;
        } else {            // K -> fragment-contiguous K4 layout (bf16)
          int hh = cg >> 6, dd = cg & 63;
          int kk = dd >> 5, qv_ = (dd >> 3) & 3, iv = dd & 7;
          size_t base = (((size_t)(bb * 16 + hh) * 16 + jt) * 16 + kk * 8);
#pragma unroll
          for (int r = 0; r < 4; ++r) {
            int tpr = tp + r;
            int njr = tpr >> 4, l15r = tpr & 15;
            Kb[((base + njr) * 64 + qv_ * 16 + l15r) * 8 + iv] = f2bf(acc[mi][ni][r]);
          }
        }
      } else if (prob == 1) {
        float uu = f32g ? ((const float*)ub)[cg] : bf2f(((const u16*)ub)[cg]);
        float vv = f32g ? ((const float*)vb)[cg] : bf2f(((const u16*)vb)[cg]);
#pragma unroll
        for (int r = 0; r < 4; ++r) {
          size_t ci = (size_t)(rg0 + r) * 1024 + cg;
          QU[ci] = f2bf(acc[mi][ni][r] + uu);
          QV[ci] = f2bf(acc[mi][ni][r] + vv);
        }
      } else {
#pragma unroll
        for (int r = 0; r < 4; ++r)
          Pb[(size_t)(rg0 + r) * 1024 + cg] = f2bf(acc[mi][ni][r]);
      }
    }
  }
}

// ---------------------------------------------------------------------------
// out projection GEMM, 64x128 tiles -> 512 blocks (2 blocks/CU).
// ---------------------------------------------------------------------------
__global__ __launch_bounds__(256) void gemm_out(
    const u16* __restrict__ A, const u16* __restrict__ BT,
    void* __restrict__ Cp, const int* __restrict__ dflag)
{
  __shared__ __align__(16) u16 As[2][64][40];
  __shared__ __align__(16) u16 Bs[2][128][40];
  const int f32g = dflag[0];
  const int tid = threadIdx.x;
  const int w = tid >> 6, lane = tid & 63, quad = lane >> 4, l15 = lane & 15;
  const int wr = w >> 1, wc = w & 1;
  const int m0 = blockIdx.y * 64, n0 = blockIdx.x * 128;
  const int srow = tid >> 2, sc8 = (tid & 3) * 8;   // srow in [0,64)

  const u16* apr0 = A + (size_t)(m0 + srow) * 1024 + sc8;
  const u16* bpr0 = BT + (size_t)(n0 + srow) * 1024 + sc8;
  const u16* bpr1 = BT + (size_t)(n0 + 64 + srow) * 1024 + sc8;

  float4v acc[2][4];
#pragma unroll
  for (int i = 0; i < 2; ++i)
#pragma unroll
    for (int j = 0; j < 4; ++j) acc[i][j] = (float4v){0.f, 0.f, 0.f, 0.f};

  uint4 aR0 = *(const uint4*)(apr0);
  uint4 bR0 = *(const uint4*)(bpr0);
  uint4 bR1 = *(const uint4*)(bpr1);

  int p = 0;
  for (int kt = 0; kt < 1024; kt += 32, p ^= 1) {
    *(uint4*)&As[p][srow][sc8] = aR0;
    *(uint4*)&Bs[p][srow][sc8] = bR0;
    *(uint4*)&Bs[p][64 + srow][sc8] = bR1;
    __syncthreads();
    if (kt + 32 < 1024) {
      aR0 = *(const uint4*)(apr0 + kt + 32);
      bR0 = *(const uint4*)(bpr0 + kt + 32);
      bR1 = *(const uint4*)(bpr1 + kt + 32);
    }
    short8 af[2], bf[4];
#pragma unroll
    for (int mi = 0; mi < 2; ++mi)
      af[mi] = *(const short8*)&As[p][wr * 32 + mi * 16 + l15][quad * 8];
#pragma unroll
    for (int ni = 0; ni < 4; ++ni)
      bf[ni] = *(const short8*)&Bs[p][wc * 64 + ni * 16 + l15][quad * 8];
#pragma unroll
    for (int mi = 0; mi < 2; ++mi)
#pragma unroll
      for (int ni = 0; ni < 4; ++ni)
        acc[mi][ni] = __builtin_amdgcn_mfma_f32_16x16x32_bf16(af[mi], bf[ni], acc[mi][ni], 0, 0, 0);
    // single barrier per K-step (dbuf)
  }

#pragma unroll
  for (int mi = 0; mi < 2; ++mi) {
#pragma unroll
    for (int ni = 0; ni < 4; ++ni) {
      int rg0 = m0 + wr * 32 + mi * 16 + quad * 4;
      int cg = n0 + wc * 64 + ni * 16 + l15;
#pragma unroll
      for (int r = 0; r < 4; ++r) {
        size_t ci = (size_t)(rg0 + r) * 1024 + cg;
        float va = acc[mi][ni][r];
        if (f32g) ((float*)Cp)[ci] = va;
        else      ((u16*)Cp)[ci] = f2bf(va);
      }
    }
  }
}

// band-element load: resolves rel-shift row for column dd, zero at jp==0
#define BLD(itc) ({ \
  int dd_ = ddmN + (itc) * 32 + trow; \
  int q2_ = (dd_ >= 2049) + (dd_ >= 4098); \
  int jp_ = dd_ - 2049 * q2_; \
  uint4 pv_ = *(const uint4*)(PbH + (size_t)((jp_ > 0) ? jp_ - 1 : 0) * 1024); \
  uint4 z4_ = {0u, 0u, 0u, 0u}; \
  (jp_ == 0) ? z4_ : pv_; })

// band fragment: rows (q+v) x band cols, with rel-shift threshold crossing merge
#define BANDFRAG(fc, dst) { \
      int dds = ddminW + (fc) * 16; \
      int qlo = (dds >= 2049) + (dds >= 4098); \
      int qhi = (dds + 15 >= 2049) + (dds + 15 >= 4098); \
      if (qlo != q2c) { \
        const u16* ar = &qvs[16 * w + l15 + qlo][0]; \
        a0 = *(const short8*)(ar + quad * 8); \
        a1 = *(const short8*)(ar + 32 + quad * 8); \
        q2c = qlo; \
      } \
      const u16* br = &band[(toff + (fc) * 16 + l15) * 72]; \
      short8 b0 = *(const short8*)(br + quad * 8); \
      short8 b1 = *(const short8*)(br + 32 + quad * 8); \
      float4v c = (float4v){0.f, 0.f, 0.f, 0.f}; \
      c = __builtin_amdgcn_mfma_f32_16x16x32_bf16(a0, b0, c, 0, 0, 0); \
      c = __builtin_amdgcn_mfma_f32_16x16x32_bf16(a1, b1, c, 0, 0, 0); \
      if (qhi != qlo) { \
        const u16* ar2 = &qvs[16 * w + l15 + qhi][0]; \
        short8 e0 = *(const short8*)(ar2 + quad * 8); \
        short8 e1 = *(const short8*)(ar2 + 32 + quad * 8); \
        float4v c2 = (float4v){0.f, 0.f, 0.f, 0.f}; \
        c2 = __builtin_amdgcn_mfma_f32_16x16x32_bf16(e0, b0, c2, 0, 0, 0); \
        c2 = __builtin_amdgcn_mfma_f32_16x16x32_bf16(e1, b1, c2, 0, 0, 0); \
        int colX = ((qlo == 0) ? 2049 : 4098) - dds; \
        bool useHi = (l15 >= colX); \
        for (int rr = 0; rr < 4; ++rr) c[rr] = useHi ? c2[rr] : c[rr]; \
      } \
      dst = c; }

// ---------------------------------------------------------------------------
// Fused flash attention. Round-12 delta vs verified round-6 (177.4us): the
// kernel is DS-pipe-THROUGHPUT-bound (~1000 DS-cyc/wave-tile x 8 waves ~= the
// wall; occupancy attempts r7/r11 proved extra blocks don't help). K staging
// + QK fragment reads were 20 of ~52 b128 DS ops/wave-tile — K now lives in
// the fragment-contiguous K4 global layout (V4 pattern): 16 coalesced 1KB
// loads per tile into registers, prefetched one tile ahead (issued right
// after QK, landing under band-MFMA+softmax+PV). Ks LDS buffer removed
// (62976 -> ~46.4KB). VGPR +~48 (cap 256 under (256,2) — no spill expected;
// WRITE_SIZE is the tripwire).
// ---------------------------------------------------------------------------
__global__ __launch_bounds__(256, 2) void attn_fused(
    const u16* __restrict__ QU, const u16* __restrict__ QV,
    const u16* __restrict__ Kb, const u16* __restrict__ VT,
    const u16* __restrict__ Pb, u16* __restrict__ AWV)
{
  __shared__ __align__(16) u16 band[192 * 72];   // p-band
  __shared__ __align__(16) u16 qvs[66][72];      // (q+v) rows [m0..m0+65] bf16
  __shared__ __align__(16) u16 Ps[4 * 16 * 72];  // per-wave P slices (fp16)
  const int b = blockIdx.z, h = blockIdx.y;
  const int i0 = (15 - blockIdx.x) * 64;         // big blocks first
  const int tid = threadIdx.x, w = tid >> 6, lane = tid & 63;
  const int quad = lane >> 4, l15 = lane & 15;
  const int iw = i0 + w * 16;
  const int m0 = b * 1024 + i0;
  const int MQ = 5120 - 1024 * b;                // dd <= MQ <=> unmasked

  // content-Q fragment (q+u)
  const size_t qb = ((size_t)(b * 1024 + iw + l15)) * 1024 + h * 64 + quad * 8;
  short8 qf0 = *(const short8*)(QU + qb);
  short8 qf1 = *(const short8*)(QU + qb + 32);

  // stage qv rows once per block (66 rows x 64 d)
#pragma unroll
  for (int it = 0; it < 3; ++it) {
    int slot = it * 256 + tid;
    if (slot < 528) {
      int row = slot >> 3, d8q = (slot & 7) * 8;
      int gr = m0 + row; if (gr > 4095) gr = 4095;   // tail rows never used in-mask
      *(uint4*)&qvs[row][d8q] = *(const uint4*)(QV + (size_t)gr * 1024 + h * 64 + d8q);
    }
  }

  float4v o[4];
#pragma unroll
  for (int ni = 0; ni < 4; ++ni) o[ni] = (float4v){0.f, 0.f, 0.f, 0.f};
  float mrun[4] = {NEG_BIG, NEG_BIG, NEG_BIG, NEG_BIG};
  float lrun[4] = {0.f, 0.f, 0.f, 0.f};

  const int toff = 48 - 16 * w;                  // wave band offset in block band
  const int nT = (i0 + 1088 + 127) / 128;

  // fixed per-thread staging slots + hoisted base pointers
  const int trow = tid >> 3, d8 = (tid & 7) * 8;   // band staging
  const u16* PbH = Pb + h * 64 + d8;
  // K4 fragment base: per (b,h) chunk of 131072 halves, +lane*8
  const u16* Kf = Kb + (size_t)(b * 16 + h) * 131072 + (size_t)lane * 8;
  // V4 fragment base: per (b,h) chunk of 131072 halves, +lane*8
  const u16* Vg = VT + (size_t)(b * 16 + h) * 131072 + (size_t)lane * 8;
  const int ddm0 = 4096 - m0 - 63 + trow;          // dd at (j0=0, it=0)

  // ---- prologue: prefetch tile 0 (band regs + all 16 K fragments) ----
  int ddmN = ddm0 - trow;   // BLD adds trow back
  uint4 bRa = BLD(0), bRb = BLD(1), bRc = BLD(2), bRd = BLD(3), bRe = BLD(4), bRf = BLD(5);
  short8 kf[16];
#pragma unroll
  for (int f = 0; f < 16; ++f) kf[f] = *(const short8*)(Kf + f * 512);

  for (int jt = 0; jt < nT; ++jt) {
    const int j0 = jt * 128;
    const int ddminB = j0 + 4096 - (m0 + 63);
    const u16* VgT = Vg + (size_t)jt * 8192;

    // ---- LDS write phase (band only; K is register-resident) ----
    *(uint4*)&band[(0 * 32 + trow) * 72 + d8] = bRa;
    *(uint4*)&band[(1 * 32 + trow) * 72 + d8] = bRb;
    *(uint4*)&band[(2 * 32 + trow) * 72 + d8] = bRc;
    *(uint4*)&band[(3 * 32 + trow) * 72 + d8] = bRd;
    *(uint4*)&band[(4 * 32 + trow) * 72 + d8] = bRe;
    *(uint4*)&band[(5 * 32 + trow) * 72 + d8] = bRf;
    __syncthreads();

    // ---- issue next tile's band loads (drain overlaps this tile's compute) ----
    if (jt + 1 < nT) {
      ddmN = j0 + 128 + 4096 - m0 - 63;
      bRa = BLD(0); bRb = BLD(1); bRc = BLD(2);
      bRd = BLD(3); bRe = BLD(4); bRf = BLD(5);
    }

    // ---- content QK^T (K fragments from registers) ----
    float4v sc[8];
    __builtin_amdgcn_s_setprio(1);
#pragma unroll
    for (int nj = 0; nj < 8; ++nj) {
      float4v s = (float4v){0.f, 0.f, 0.f, 0.f};
      s = __builtin_amdgcn_mfma_f32_16x16x32_bf16(qf0, kf[nj], s, 0, 0, 0);
      s = __builtin_amdgcn_mfma_f32_16x16x32_bf16(qf1, kf[8 + nj], s, 0, 0, 0);
      sc[nj] = s;
    }
    __builtin_amdgcn_s_setprio(0);

    // ---- issue next tile's K fragment loads (land under band/softmax/PV) ----
    if (jt + 1 < nT) {
      const u16* KfT = Kf + (size_t)(jt + 1) * 8192;
#pragma unroll
      for (int f = 0; f < 16; ++f) kf[f] = *(const short8*)(KfT + f * 512);
    }

    // ---- positional band MFMA in two 5-frag halves + interleaved extraction ----
    const int ddminW = ddminB + toff;
    const int tmaxW = MQ - ddminW;
    float4v bc[5];
    int q2c = -1;
    short8 a0, a1;
    __builtin_amdgcn_s_setprio(1);
    BANDFRAG(0, bc[0])
    BANDFRAG(1, bc[1])
    BANDFRAG(2, bc[2])
    BANDFRAG(3, bc[3])
    BANDFRAG(4, bc[4])
    __builtin_amdgcn_s_setprio(0);
    // extract njs 0..3 (uses bc[0..4])
#pragma unroll
    for (int r = 0; r < 4; ++r) {
      const int tb = 15 - quad * 4 - r;                      // in [0,15]
      const int adr = 4 * (((l15 + tb) & 15) + 16 * quad);   // source lane (same quad)
      const bool srcHi = (l15 < tb);
#pragma unroll
      for (int nj = 0; nj < 4; ++nj) {
        float mg = srcHi ? bc[nj + 1][r] : bc[nj][r];
        int p = __builtin_amdgcn_ds_bpermute(adr, __float_as_int(mg));
        float pos = __int_as_float(p);
        float v2 = (sc[nj][r] + pos) * SCL2;
        int tw = nj * 16 + l15 + tb;
        sc[nj][r] = (tw <= tmaxW) ? v2 : NEG_BIG;
      }
    }
    bc[0] = bc[4];
    __builtin_amdgcn_s_setprio(1);
    BANDFRAG(5, bc[1])
    BANDFRAG(6, bc[2])
    BANDFRAG(7, bc[3])
    BANDFRAG(8, bc[4])
    __builtin_amdgcn_s_setprio(0);
    // extract njs 4..7 (uses bc[0..4] = frags 4..8)
#pragma unroll
    for (int r = 0; r < 4; ++r) {
      const int tb = 15 - quad * 4 - r;
      const int adr = 4 * (((l15 + tb) & 15) + 16 * quad);
      const bool srcHi = (l15 < tb);
#pragma unroll
      for (int nj = 4; nj < 8; ++nj) {
        float mg = srcHi ? bc[nj - 3][r] : bc[nj - 4][r];
        int p = __builtin_amdgcn_ds_bpermute(adr, __float_as_int(mg));
        float pos = __int_as_float(p);
        float v2 = (sc[nj][r] + pos) * SCL2;
        int tw = nj * 16 + l15 + tb;
        sc[nj][r] = (tw <= tmaxW) ? v2 : NEG_BIG;
      }
    }

    // ---- V fragments group (hk0,kc0): land under softmax ----
    short8 va0 = *(const short8*)(VgT);
    short8 va1 = *(const short8*)(VgT + 512);
    short8 va2 = *(const short8*)(VgT + 1024);
    short8 va3 = *(const short8*)(VgT + 1536);

    // ---- online softmax (log2 domain); reductions on VALU via DPP ror ----
#pragma unroll
    for (int r = 0; r < 4; ++r) {
      float mx = sc[0][r];
#pragma unroll
      for (int nj = 1; nj < 8; ++nj) mx = fmaxf(mx, sc[nj][r]);
      mx = fmaxf(mx, ROR16(mx, 8));
      mx = fmaxf(mx, ROR16(mx, 4));
      mx = fmaxf(mx, ROR16(mx, 2));
      mx = fmaxf(mx, ROR16(mx, 1));
      float mnew = fmaxf(mrun[r], mx);
      float al = exp2f(mrun[r] - mnew);
      float rs = 0.f;
#pragma unroll
      for (int nj = 0; nj < 8; ++nj) {
        float pv = exp2f(sc[nj][r] - mnew);
        sc[nj][r] = pv;
        rs += pv;
      }
      rs += ROR16(rs, 8);
      rs += ROR16(rs, 4);
      rs += ROR16(rs, 2);
      rs += ROR16(rs, 1);
      lrun[r] = lrun[r] * al + rs;
      mrun[r] = mnew;
#pragma unroll
      for (int ni = 0; ni < 4; ++ni) o[ni][r] *= al;
    }

    // ---- V fragments group (hk0,kc1) ----
    short8 vb0 = *(const short8*)(VgT + 2048);
    short8 vb1 = *(const short8*)(VgT + 2560);
    short8 vb2 = *(const short8*)(VgT + 3072);
    short8 vb3 = *(const short8*)(VgT + 3584);

    // ---- P pack (fp16, per-wave Ps slice) + PV (V from registers) ----
    u16* Psw = Ps + w * 1152;   // [16][72]
    // hk = 0 pack
#pragma unroll
    for (int nj = 0; nj < 4; ++nj)
#pragma unroll
      for (int r = 0; r < 4; ++r)
        Psw[(quad * 4 + r) * 72 + nj * 16 + l15] = f2h(sc[nj][r]);
    {  // (hk=0, kc=0)
      short8 ap = *(const short8*)&Psw[l15 * 72 + quad * 8];
      __builtin_amdgcn_s_setprio(1);
      o[0] = __builtin_amdgcn_mfma_f32_16x16x32_f16(ap, va0, o[0], 0, 0, 0);
      o[1] = __builtin_amdgcn_mfma_f32_16x16x32_f16(ap, va1, o[1], 0, 0, 0);
      o[2] = __builtin_amdgcn_mfma_f32_16x16x32_f16(ap, va2, o[2], 0, 0, 0);
      o[3] = __builtin_amdgcn_mfma_f32_16x16x32_f16(ap, va3, o[3], 0, 0, 0);
      __builtin_amdgcn_s_setprio(0);
    }
    // refill for (hk=1, kc=0)
    va0 = *(const short8*)(VgT + 4096);
    va1 = *(const short8*)(VgT + 4608);
    va2 = *(const short8*)(VgT + 5120);
    va3 = *(const short8*)(VgT + 5632);
    {  // (hk=0, kc=1)
      short8 ap = *(const short8*)&Psw[l15 * 72 + 32 + quad * 8];
      __builtin_amdgcn_s_setprio(1);
      o[0] = __builtin_amdgcn_mfma_f32_16x16x32_f16(ap, vb0, o[0], 0, 0, 0);
      o[1] = __builtin_amdgcn_mfma_f32_16x16x32_f16(ap, vb1, o[1], 0, 0, 0);
      o[2] = __builtin_amdgcn_mfma_f32_16x16x32_f16(ap, vb2, o[2], 0, 0, 0);
      o[3] = __builtin_amdgcn_mfma_f32_16x16x32_f16(ap, vb3, o[3], 0, 0, 0);
      __builtin_amdgcn_s_setprio(0);
    }
    // refill for (hk=1, kc=1)
    vb0 = *(const short8*)(VgT + 6144);
    vb1 = *(const short8*)(VgT + 6656);
    vb2 = *(const short8*)(VgT + 7168);
    vb3 = *(const short8*)(VgT + 7680);
    // hk = 1 pack (same-wave LDS write->read: DS pipe is in-order per wave)
#pragma unroll
    for (int nj = 0; nj < 4; ++nj)
#pragma unroll
      for (int r = 0; r < 4; ++r)
        Psw[(quad * 4 + r) * 72 + nj * 16 + l15] = f2h(sc[4 + nj][r]);
    {  // (hk=1, kc=0)
      short8 ap = *(const short8*)&Psw[l15 * 72 + quad * 8];
      __builtin_amdgcn_s_setprio(1);
      o[0] = __builtin_amdgcn_mfma_f32_16x16x32_f16(ap, va0, o[0], 0, 0, 0);
      o[1] = __builtin_amdgcn_mfma_f32_16x16x32_f16(ap, va1, o[1], 0, 0, 0);
      o[2] = __builtin_amdgcn_mfma_f32_16x16x32_f16(ap, va2, o[2], 0, 0, 0);
      o[3] = __builtin_amdgcn_mfma_f32_16x16x32_f16(ap, va3, o[3], 0, 0, 0);
      __builtin_amdgcn_s_setprio(0);
    }
    {  // (hk=1, kc=1)
      short8 ap = *(const short8*)&Psw[l15 * 72 + 32 + quad * 8];
      __builtin_amdgcn_s_setprio(1);
      o[0] = __builtin_amdgcn_mfma_f32_16x16x32_f16(ap, vb0, o[0], 0, 0, 0);
      o[1] = __builtin_amdgcn_mfma_f32_16x16x32_f16(ap, vb1, o[1], 0, 0, 0);
      o[2] = __builtin_amdgcn_mfma_f32_16x16x32_f16(ap, vb2, o[2], 0, 0, 0);
      o[3] = __builtin_amdgcn_mfma_f32_16x16x32_f16(ap, vb3, o[3], 0, 0, 0);
      __builtin_amdgcn_s_setprio(0);
    }
    __syncthreads();   // all band reads done; next tile may overwrite
  }

#pragma unroll
  for (int r = 0; r < 4; ++r) {
    float inv = 1.0f / lrun[r];
#pragma unroll
    for (int ni = 0; ni < 4; ++ni) {
      AWV[((size_t)(b * 1024 + iw + quad * 4 + r)) * 1024 + h * 64 + ni * 16 + l15] =
          f2bf(o[ni][r] * inv);
    }
  }
}

// ---------------------------------------------------------------------------
extern "C" void kernel_launch(void* const* d_in, const int* in_sizes, int n_in,
                              void* d_out, int out_size, void* d_ws, size_t ws_size,
                              hipStream_t stream) {
  const void* input_ = d_in[0];
  const void* pose   = d_in[1];
  const void* memry  = d_in[2];
  const void* ubias  = d_in[3];
  const void* vbias  = d_in[4];
  const void* Wkv    = d_in[5];
  const void* Wq     = d_in[6];
  const void* Wp     = d_in[7];
  const void* Wout   = d_in[8];
  // d_in[9] (mask) unused: mask is j <= i + 1024, computed analytically.

  char* base = (char*)d_ws;
  size_t off = 0;
  auto carve = [&](size_t bytes) {
    void* r = base + off;
    off += (bytes + 255) & ~(size_t)255;
    return r;
  };
  int* dflag = (int*)carve(256);
  u16* Kb    = (u16*)carve((size_t)4 * 2048 * 1024 * 2);   // K4 fragment layout, bf16
  u16* VT    = (u16*)carve((size_t)1024 * 4 * 2048 * 2);   // V4 fragment layout, fp16
  u16* QU    = (u16*)carve((size_t)4 * 1024 * 1024 * 2);
  u16* QV    = (u16*)carve((size_t)4 * 1024 * 1024 * 2);
  u16* Pb    = (u16*)carve((size_t)2048 * 1024 * 2);
  u16* AWVb  = (u16*)carve((size_t)4 * 1024 * 1024 * 2);
  u16* WkvT  = (u16*)carve((size_t)2048 * 1024 * 2);
  u16* WqT   = (u16*)carve((size_t)1024 * 1024 * 2);
  u16* WpT   = (u16*)carve((size_t)1024 * 1024 * 2);
  u16* WoutT = (u16*)carve((size_t)1024 * 1024 * 2);
  u16* inpB  = (u16*)carve((size_t)4 * 1024 * 1024 * 2);
  u16* memB  = (u16*)carve((size_t)4 * 1024 * 1024 * 2);
  u16* poseB = (u16*)carve((size_t)2048 * 1024 * 2);

  detect_dtype<<<1, 64, 0, stream>>>((const unsigned*)input_, dflag);
  // merged converts + weight transposes (one dispatch)
  prep_all<<<dim3(15360, 1, 1), 256, 0, stream>>>(
      input_, memry, pose, inpB, memB, poseB,
      Wkv, Wq, Wp, Wout, WkvT, WqT, WpT, WoutT, dflag);

  // merged projections: kv (1024 blocks) + q (256) + p (128) in one dispatch
  gemm_proj<<<dim3(1408, 1, 1), 256, 0, stream>>>(
      memB, inpB, poseB, WkvT, WqT, WpT,
      Kb, VT, QU, QV, Pb, ubias, vbias, dflag, 1024);

  // fused attention, all 16 heads in one dispatch (1024 blocks)
  attn_fused<<<dim3(16, 16, 4), 256, 0, stream>>>(QU, QV, Kb, VT, Pb, AWVb);

  // out = awv @ W_out  (M=4096, N=1024, K=1024), 64x128 tiles = 512 blocks
  gemm_out<<<dim3(8, 64, 1), 256, 0, stream>>>(AWVb, WoutT, d_out, dflag);
}

// Round 13
// 379.922 us; speedup vs baseline: 1.0280x; 1.0280x over previous
//
#include <hip/hip_runtime.h>

typedef unsigned short u16;
typedef __attribute__((ext_vector_type(8))) short short8;
typedef __attribute__((ext_vector_type(4))) float float4v;

#define SCL2 (0.125f * 1.44269504088896340736f)   // logit scale folded into log2 domain
#define NEG_BIG -1.0e8f

// 16-lane rotation on the VALU pipe (DPP row_ror) — replaces shfl_xor (DS pipe)
#define ROR16(x, N) __int_as_float(__builtin_amdgcn_mov_dpp( \
    __float_as_int(x), 0x120 + (N), 0xF, 0xF, true))

static __device__ __forceinline__ u16 f2bf(float f) {
  union { float f; unsigned u; } x; x.f = f;
  unsigned r = x.u + 0x7fffu + ((x.u >> 16) & 1u);
  return (u16)(r >> 16);
}
static __device__ __forceinline__ float bf2f(u16 b) {
  union { unsigned u; float f; } x; x.u = ((unsigned)b) << 16;
  return x.f;
}
static __device__ __forceinline__ u16 f2h(float f) {
  union { u16 u; _Float16 h; } x; x.h = (_Float16)f; return x.u;
}

// ---------------------------------------------------------------------------
__global__ void detect_dtype(const unsigned* __restrict__ in0, int* __restrict__ flag) {
  if (threadIdx.x == 0 && blockIdx.x == 0) {
    int cnt = 0;
    for (int i = 0; i < 256; ++i) {
      unsigned e = (in0[i] >> 7) & 0xFFu;
      if (e >= 100u && e <= 140u) cnt++;
    }
    flag[0] = (cnt < 128) ? 1 : 0;
  }
}

// ---------------------------------------------------------------------------
// Merged prep: converts (input/memory/pose -> bf16) + 4 weight transposes in
// ONE dispatch (block-range table, all branches block-uniform).
// ---------------------------------------------------------------------------
__global__ __launch_bounds__(256) void prep_all(
    const void* __restrict__ A0, const void* __restrict__ A1, const void* __restrict__ A2,
    u16* __restrict__ O0, u16* __restrict__ O1, u16* __restrict__ O2,
    const void* __restrict__ W0, const void* __restrict__ W1,
    const void* __restrict__ W2, const void* __restrict__ W3,
    u16* __restrict__ T0, u16* __restrict__ T1,
    u16* __restrict__ T2, u16* __restrict__ T3,
    const int* __restrict__ dflag) {
  __shared__ __align__(16) u16 t[32][33];
  const int bid = blockIdx.x, tid = threadIdx.x;
  const int f32 = dflag[0];

  if (bid < 10240) {  // ---- converts ----
    int z = (bid < 4096) ? 0 : (bid < 8192) ? 1 : 2;
    int lb = bid - ((z == 0) ? 0 : (z == 1) ? 4096 : 8192);
    const void* in = (z == 0) ? A0 : (z == 1) ? A1 : A2;
    u16* out = (z == 0) ? O0 : (z == 1) ? O1 : O2;
    int i = (lb * 256 + tid) * 4;
    if (f32) {
      float4 v = *(const float4*)((const float*)in + i);
      u16 o[4] = {f2bf(v.x), f2bf(v.y), f2bf(v.z), f2bf(v.w)};
      *(uint2*)(out + i) = *(uint2*)o;
    } else {
      *(uint2*)(out + i) = *(const uint2*)((const u16*)in + i);
    }
    return;
  }
  // ---- transposes ----
  int z, lb;
  if (bid < 12288)      { z = 0; lb = bid - 10240; }
  else if (bid < 13312) { z = 1; lb = bid - 12288; }
  else if (bid < 14336) { z = 2; lb = bid - 13312; }
  else                  { z = 3; lb = bid - 14336; }
  const void* in = (z == 0) ? W0 : (z == 1) ? W1 : (z == 2) ? W2 : W3;
  u16* out = (z == 0) ? T0 : (z == 1) ? T1 : (z == 2) ? T2 : T3;
  const int C = (z == 0) ? 2048 : 1024;
  const int nbx = C / 32;
  const int bx = lb % nbx, by = lb / nbx;
  const int tx = tid & 31, ty = tid >> 5;            // 32x8
  int c = bx * 32 + tx;
  int rbase = by * 32;
#pragma unroll
  for (int k = 0; k < 4; ++k) {
    int r = rbase + ty + k * 8;
    size_t idx = (size_t)r * C + c;
    t[ty + k * 8][tx] = f32 ? f2bf(((const float*)in)[idx]) : ((const u16*)in)[idx];
  }
  __syncthreads();
  int r2 = rbase + tx;
#pragma unroll
  for (int k = 0; k < 4; ++k) {
    int c2 = bx * 32 + ty + k * 8;
    out[(size_t)c2 * 1024 + r2] = t[tx][ty + k * 8];
  }
}

// row pointer for A (or gathered [gmem;ginp] concat when A==nullptr)
static __device__ __forceinline__ const u16* gemm_arow(
    const u16* A, const u16* gmem, const u16* ginp,
    int lda, long aOff, long aZ, int z, int rg) {
  if (A) return A + (size_t)rg * lda + aOff + (long)z * aZ;
  int bb = rg >> 11, t = rg & 2047;
  return (t < 1024) ? (gmem + ((size_t)(bb * 1024 + t)) * 1024)
                    : (ginp + ((size_t)(bb * 1024 + t - 1024)) * 1024);
}

// ---------------------------------------------------------------------------
// Merged projection GEMM: kv + q + p in ONE dispatch (1408 blocks) — verified
// round-9/10. Body = round-8 loop (reg-prefetch + LDS dbuf, 1 barrier/K-step).
// K written row-major (r10-verified; r12's K4 fragment layout regressed).
// V4 fragment layout: V4[(((b*16+h)*16+jt)*16+f)*64+lane][i] (fp16)
// ---------------------------------------------------------------------------
__global__ __launch_bounds__(256) void gemm_proj(
    const u16* __restrict__ memB, const u16* __restrict__ inpB,
    const u16* __restrict__ poseB,
    const u16* __restrict__ WkvT, const u16* __restrict__ WqT,
    const u16* __restrict__ WpT,
    u16* __restrict__ Kb, u16* __restrict__ VT,
    u16* __restrict__ QU, u16* __restrict__ QV, u16* __restrict__ Pb,
    const void* __restrict__ ub, const void* __restrict__ vb,
    const int* __restrict__ dflag, int K)
{
  __shared__ __align__(16) u16 As[2][128][40];
  __shared__ __align__(16) u16 Bs[2][128][40];
  const int f32g = dflag[0];
  const int tid = threadIdx.x;
  const int w = tid >> 6, lane = tid & 63, quad = lane >> 4, l15 = lane & 15;
  const int wr = w >> 1, wc = w & 1;
  const int srow = tid >> 2, sc8 = (tid & 3) * 8;

  const int bid = blockIdx.x;
  int prob, bx, by;
  if (bid < 1024)      { prob = 0; bx = bid & 15; by = bid >> 4; }
  else if (bid < 1280) { int t = bid - 1024; prob = 1; bx = t & 7; by = t >> 3; }
  else                 { int t = bid - 1280; prob = 2; bx = t & 7; by = t >> 3; }
  const int m0 = by * 128, n0 = bx * 128;
  const u16* BT = (prob == 0) ? WkvT : (prob == 1) ? WqT : WpT;

  const u16 *apr0, *apr1;
  if (prob == 0) {
    apr0 = gemm_arow(nullptr, memB, inpB, 0, 0, 0, 0, m0 + srow) + sc8;
    apr1 = gemm_arow(nullptr, memB, inpB, 0, 0, 0, 0, m0 + 64 + srow) + sc8;
  } else {
    const u16* Ab = (prob == 1) ? inpB : poseB;
    apr0 = Ab + (size_t)(m0 + srow) * 1024 + sc8;
    apr1 = Ab + (size_t)(m0 + 64 + srow) * 1024 + sc8;
  }
  const u16* bpr0 = BT + (size_t)(n0 + srow) * 1024 + sc8;
  const u16* bpr1 = BT + (size_t)(n0 + 64 + srow) * 1024 + sc8;

  float4v acc[4][4];
#pragma unroll
  for (int i = 0; i < 4; ++i)
#pragma unroll
    for (int j = 0; j < 4; ++j) acc[i][j] = (float4v){0.f, 0.f, 0.f, 0.f};

  uint4 aR0 = *(const uint4*)(apr0);
  uint4 aR1 = *(const uint4*)(apr1);
  uint4 bR0 = *(const uint4*)(bpr0);
  uint4 bR1 = *(const uint4*)(bpr1);

  int p = 0;
  for (int kt = 0; kt < K; kt += 32, p ^= 1) {
    *(uint4*)&As[p][srow][sc8] = aR0;
    *(uint4*)&As[p][64 + srow][sc8] = aR1;
    *(uint4*)&Bs[p][srow][sc8] = bR0;
    *(uint4*)&Bs[p][64 + srow][sc8] = bR1;
    __syncthreads();
    if (kt + 32 < K) {
      aR0 = *(const uint4*)(apr0 + kt + 32);
      aR1 = *(const uint4*)(apr1 + kt + 32);
      bR0 = *(const uint4*)(bpr0 + kt + 32);
      bR1 = *(const uint4*)(bpr1 + kt + 32);
    }
    short8 af[4], bf[4];
#pragma unroll
    for (int mi = 0; mi < 4; ++mi)
      af[mi] = *(const short8*)&As[p][wr * 64 + mi * 16 + l15][quad * 8];
#pragma unroll
    for (int ni = 0; ni < 4; ++ni)
      bf[ni] = *(const short8*)&Bs[p][wc * 64 + ni * 16 + l15][quad * 8];
#pragma unroll
    for (int mi = 0; mi < 4; ++mi)
#pragma unroll
      for (int ni = 0; ni < 4; ++ni)
        acc[mi][ni] = __builtin_amdgcn_mfma_f32_16x16x32_bf16(af[mi], bf[ni], acc[mi][ni], 0, 0, 0);
    // single barrier per K-step: next iter writes the OTHER buffer
  }

#pragma unroll
  for (int mi = 0; mi < 4; ++mi) {
#pragma unroll
    for (int ni = 0; ni < 4; ++ni) {
      int rg0 = m0 + wr * 64 + mi * 16 + quad * 4;
      int cg = n0 + wc * 64 + ni * 16 + l15;
      if (prob == 0) {
        if (cg >= 1024) {   // V -> fragment-contiguous V4 layout (fp16)
          int d_full = cg - 1024;
          int hh = d_full >> 6, dd = d_full & 63;
          int niv = dd >> 4, lv = dd & 15;
          int bb = rg0 >> 11, t0 = rg0 & 2047;
          int jt = t0 >> 7, tp = t0 & 127;
          int f = ((tp >> 5) << 2) + niv;
          int lanev = ((tp >> 3) & 3) * 16 + lv;
          int iv = tp & 7;
          size_t Aidx = ((((size_t)(bb * 16 + hh) * 16 + jt) * 16 + f) * 64 + lanev) * 8 + iv;
          u16 h4[4] = {f2h(acc[mi][ni][0]), f2h(acc[mi][ni][1]),
                       f2h(acc[mi][ni][2]), f2h(acc[mi][ni][3])};
          *(uint2*)&VT[Aidx] = *(uint2*)h4;
        } else {
#pragma unroll
          for (int r = 0; r < 4; ++r)
            Kb[(size_t)(rg0 + r) * 1024 + cg] = f2bf(acc[mi][ni][r]);
        }
      } else if (prob == 1) {
        float uu = f32g ? ((const float*)ub)[cg] : bf2f(((const u16*)ub)[cg]);
        float vv = f32g ? ((const float*)vb)[cg] : bf2f(((const u16*)vb)[cg]);
#pragma unroll
        for (int r = 0; r < 4; ++r) {
          size_t ci = (size_t)(rg0 + r) * 1024 + cg;
          QU[ci] = f2bf(acc[mi][ni][r] + uu);
          QV[ci] = f2bf(acc[mi][ni][r] + vv);
        }
      } else {
#pragma unroll
        for (int r = 0; r < 4; ++r)
          Pb[(size_t)(rg0 + r) * 1024 + cg] = f2bf(acc[mi][ni][r]);
      }
    }
  }
}

// ---------------------------------------------------------------------------
// out projection GEMM, 64x128 tiles -> 512 blocks (2 blocks/CU).
// ---------------------------------------------------------------------------
__global__ __launch_bounds__(256) void gemm_out(
    const u16* __restrict__ A, const u16* __restrict__ BT,
    void* __restrict__ Cp, const int* __restrict__ dflag)
{
  __shared__ __align__(16) u16 As[2][64][40];
  __shared__ __align__(16) u16 Bs[2][128][40];
  const int f32g = dflag[0];
  const int tid = threadIdx.x;
  const int w = tid >> 6, lane = tid & 63, quad = lane >> 4, l15 = lane & 15;
  const int wr = w >> 1, wc = w & 1;
  const int m0 = blockIdx.y * 64, n0 = blockIdx.x * 128;
  const int srow = tid >> 2, sc8 = (tid & 3) * 8;   // srow in [0,64)

  const u16* apr0 = A + (size_t)(m0 + srow) * 1024 + sc8;
  const u16* bpr0 = BT + (size_t)(n0 + srow) * 1024 + sc8;
  const u16* bpr1 = BT + (size_t)(n0 + 64 + srow) * 1024 + sc8;

  float4v acc[2][4];
#pragma unroll
  for (int i = 0; i < 2; ++i)
#pragma unroll
    for (int j = 0; j < 4; ++j) acc[i][j] = (float4v){0.f, 0.f, 0.f, 0.f};

  uint4 aR0 = *(const uint4*)(apr0);
  uint4 bR0 = *(const uint4*)(bpr0);
  uint4 bR1 = *(const uint4*)(bpr1);

  int p = 0;
  for (int kt = 0; kt < 1024; kt += 32, p ^= 1) {
    *(uint4*)&As[p][srow][sc8] = aR0;
    *(uint4*)&Bs[p][srow][sc8] = bR0;
    *(uint4*)&Bs[p][64 + srow][sc8] = bR1;
    __syncthreads();
    if (kt + 32 < 1024) {
      aR0 = *(const uint4*)(apr0 + kt + 32);
      bR0 = *(const uint4*)(bpr0 + kt + 32);
      bR1 = *(const uint4*)(bpr1 + kt + 32);
    }
    short8 af[2], bf[4];
#pragma unroll
    for (int mi = 0; mi < 2; ++mi)
      af[mi] = *(const short8*)&As[p][wr * 32 + mi * 16 + l15][quad * 8];
#pragma unroll
    for (int ni = 0; ni < 4; ++ni)
      bf[ni] = *(const short8*)&Bs[p][wc * 64 + ni * 16 + l15][quad * 8];
#pragma unroll
    for (int mi = 0; mi < 2; ++mi)
#pragma unroll
      for (int ni = 0; ni < 4; ++ni)
        acc[mi][ni] = __builtin_amdgcn_mfma_f32_16x16x32_bf16(af[mi], bf[ni], acc[mi][ni], 0, 0, 0);
    // single barrier per K-step (dbuf)
  }

#pragma unroll
  for (int mi = 0; mi < 2; ++mi) {
#pragma unroll
    for (int ni = 0; ni < 4; ++ni) {
      int rg0 = m0 + wr * 32 + mi * 16 + quad * 4;
      int cg = n0 + wc * 64 + ni * 16 + l15;
#pragma unroll
      for (int r = 0; r < 4; ++r) {
        size_t ci = (size_t)(rg0 + r) * 1024 + cg;
        float va = acc[mi][ni][r];
        if (f32g) ((float*)Cp)[ci] = va;
        else      ((u16*)Cp)[ci] = f2bf(va);
      }
    }
  }
}

// band-element load: resolves rel-shift row for column dd, zero at jp==0
#define BLD(itc) ({ \
  int dd_ = ddmN + (itc) * 32 + trow; \
  int q2_ = (dd_ >= 2049) + (dd_ >= 4098); \
  int jp_ = dd_ - 2049 * q2_; \
  uint4 pv_ = *(const uint4*)(PbH + (size_t)((jp_ > 0) ? jp_ - 1 : 0) * 1024); \
  uint4 z4_ = {0u, 0u, 0u, 0u}; \
  (jp_ == 0) ? z4_ : pv_; })

// Ks packed [128 rows][64 d] bf16, XOR-swizzled 16B slots (bank-balance):
// byte addr = row*128 + (col_byte ^ ((row&7)<<4)); all accesses 16B granule.
#define KSB(row, cb) ((char*)Ks + (size_t)(row) * 128 + ((cb) ^ (((row) & 7) << 4)))
// qvs packed [66 rows][64 d] bf16, same swizzle (verified numerically in r11)
#define QSB(row, cb) ((char*)qvs + (size_t)(row) * 128 + ((cb) ^ (((row) & 7) << 4)))

// band fragment: rows (q+v) x band cols, with rel-shift threshold crossing merge
#define BANDFRAG(fc, dst) { \
      int dds = ddminW + (fc) * 16; \
      int qlo = (dds >= 2049) + (dds >= 4098); \
      int qhi = (dds + 15 >= 2049) + (dds + 15 >= 4098); \
      if (qlo != q2c) { \
        const int qr_ = 16 * w + l15 + qlo; \
        a0 = *(const short8*)QSB(qr_, quad * 16); \
        a1 = *(const short8*)QSB(qr_, 64 + quad * 16); \
        q2c = qlo; \
      } \
      const u16* br = &band[(toff + (fc) * 16 + l15) * 72]; \
      short8 b0 = *(const short8*)(br + quad * 8); \
      short8 b1 = *(const short8*)(br + 32 + quad * 8); \
      float4v c = (float4v){0.f, 0.f, 0.f, 0.f}; \
      c = __builtin_amdgcn_mfma_f32_16x16x32_bf16(a0, b0, c, 0, 0, 0); \
      c = __builtin_amdgcn_mfma_f32_16x16x32_bf16(a1, b1, c, 0, 0, 0); \
      if (qhi != qlo) { \
        const int qr2_ = 16 * w + l15 + qhi; \
        short8 e0 = *(const short8*)QSB(qr2_, quad * 16); \
        short8 e1 = *(const short8*)QSB(qr2_, 64 + quad * 16); \
        float4v c2 = (float4v){0.f, 0.f, 0.f, 0.f}; \
        c2 = __builtin_amdgcn_mfma_f32_16x16x32_bf16(e0, b0, c2, 0, 0, 0); \
        c2 = __builtin_amdgcn_mfma_f32_16x16x32_bf16(e1, b1, c2, 0, 0, 0); \
        int colX = ((qlo == 0) ? 2049 : 4098) - dds; \
        bool useHi = (l15 >= colX); \
        for (int rr = 0; rr < 4; ++rr) c[rr] = useHi ? c2[rr] : c[rr]; \
      } \
      dst = c; }

// ---------------------------------------------------------------------------
// Fused flash attention — round-6 verified structure (177.4us best), with the
// single r11-verified micro-delta: qvs packed [66][64] + XOR swizzle (fewer
// bank conflicts: 4.96e6 -> ~4.5e6 measured in r11). Dedicated Ps buffer,
// one barrier per tile, Ks in LDS, DPP softmax — all as r6/r10.
// r12's K-from-global regressed (serial-chain model, not DS-throughput) and
// is reverted.
// ---------------------------------------------------------------------------
__global__ __launch_bounds__(256, 2) void attn_fused(
    const u16* __restrict__ QU, const u16* __restrict__ QV,
    const u16* __restrict__ Kb, const u16* __restrict__ VT,
    const u16* __restrict__ Pb, u16* __restrict__ AWV)
{
  __shared__ __align__(16) u16 band[192 * 72];   // p-band
  __shared__ __align__(16) u16 Ks[128 * 64];     // K tile packed [j][d] bf16, swizzled
  __shared__ __align__(16) u16 qvs[66 * 64];     // (q+v) rows packed bf16, swizzled
  __shared__ __align__(16) u16 Ps[4 * 16 * 72];  // per-wave P slices (fp16)
  const int b = blockIdx.z, h = blockIdx.y;
  const int i0 = (15 - blockIdx.x) * 64;         // big blocks first
  const int tid = threadIdx.x, w = tid >> 6, lane = tid & 63;
  const int quad = lane >> 4, l15 = lane & 15;
  const int iw = i0 + w * 16;
  const int m0 = b * 1024 + i0;
  const int MQ = 5120 - 1024 * b;                // dd <= MQ <=> unmasked

  // content-Q fragment (q+u)
  const size_t qb = ((size_t)(b * 1024 + iw + l15)) * 1024 + h * 64 + quad * 8;
  short8 qf0 = *(const short8*)(QU + qb);
  short8 qf1 = *(const short8*)(QU + qb + 32);

  // stage qv rows once per block (66 rows x 64 d, swizzled)
#pragma unroll
  for (int it = 0; it < 3; ++it) {
    int slot = it * 256 + tid;
    if (slot < 528) {
      int row = slot >> 3, d8q = (slot & 7) * 8;
      int gr = m0 + row; if (gr > 4095) gr = 4095;   // tail rows never used in-mask
      *(uint4*)QSB(row, (slot & 7) * 16) =
          *(const uint4*)(QV + (size_t)gr * 1024 + h * 64 + d8q);
    }
  }

  float4v o[4];
#pragma unroll
  for (int ni = 0; ni < 4; ++ni) o[ni] = (float4v){0.f, 0.f, 0.f, 0.f};
  float mrun[4] = {NEG_BIG, NEG_BIG, NEG_BIG, NEG_BIG};
  float lrun[4] = {0.f, 0.f, 0.f, 0.f};

  const int toff = 48 - 16 * w;                  // wave band offset in block band
  const int nT = (i0 + 1088 + 127) / 128;

  // fixed per-thread staging slots + hoisted base pointers
  const int trow = tid >> 3, d8 = (tid & 7) * 8;   // band/Ks
  const u16* PbH = Pb + h * 64 + d8;
  const u16* KbH = Kb + ((size_t)(b * 2048 + trow)) * 1024 + h * 64 + d8;
  // V4 fragment base: per (b,h) chunk of 131072 halves, +lane*8
  const u16* Vg = VT + (size_t)(b * 16 + h) * 131072 + (size_t)lane * 8;
  const int ddm0 = 4096 - m0 - 63 + trow;          // dd at (j0=0, it=0)

  // ---- prologue: prefetch tile 0 into named registers ----
  int ddmN = ddm0 - trow;   // BLD adds trow back
  uint4 bRa = BLD(0), bRb = BLD(1), bRc = BLD(2), bRd = BLD(3), bRe = BLD(4), bRf = BLD(5);
  uint4 kRa = *(const uint4*)(KbH);
  uint4 kRb = *(const uint4*)(KbH + 32 * 1024);
  uint4 kRc = *(const uint4*)(KbH + 64 * 1024);
  uint4 kRd = *(const uint4*)(KbH + 96 * 1024);

  for (int jt = 0; jt < nT; ++jt) {
    const int j0 = jt * 128;
    const int ddminB = j0 + 4096 - (m0 + 63);
    const u16* VgT = Vg + (size_t)jt * 8192;

    // ---- LDS write phase (from prefetched registers) ----
    *(uint4*)&band[(0 * 32 + trow) * 72 + d8] = bRa;
    *(uint4*)&band[(1 * 32 + trow) * 72 + d8] = bRb;
    *(uint4*)&band[(2 * 32 + trow) * 72 + d8] = bRc;
    *(uint4*)&band[(3 * 32 + trow) * 72 + d8] = bRd;
    *(uint4*)&band[(4 * 32 + trow) * 72 + d8] = bRe;
    *(uint4*)&band[(5 * 32 + trow) * 72 + d8] = bRf;
    *(uint4*)KSB(0 * 32 + trow, (tid & 7) * 16) = kRa;
    *(uint4*)KSB(1 * 32 + trow, (tid & 7) * 16) = kRb;
    *(uint4*)KSB(2 * 32 + trow, (tid & 7) * 16) = kRc;
    *(uint4*)KSB(3 * 32 + trow, (tid & 7) * 16) = kRd;
    __syncthreads();

    // ---- issue next tile's loads (drain overlaps this tile's compute) ----
    if (jt + 1 < nT) {
      const int j0n = j0 + 128;
      ddmN = j0n + 4096 - m0 - 63;
      bRa = BLD(0); bRb = BLD(1); bRc = BLD(2);
      bRd = BLD(3); bRe = BLD(4); bRf = BLD(5);
      const u16* kp = KbH + (size_t)j0n * 1024;
      kRa = *(const uint4*)(kp);
      kRb = *(const uint4*)(kp + 32 * 1024);
      kRc = *(const uint4*)(kp + 64 * 1024);
      kRd = *(const uint4*)(kp + 96 * 1024);
    }

    // ---- content QK^T ----
    float4v sc[8];
    __builtin_amdgcn_s_setprio(1);
#pragma unroll
    for (int nj = 0; nj < 8; ++nj) {
      const int kr = nj * 16 + l15;
      short8 bk0 = *(const short8*)KSB(kr, quad * 16);
      short8 bk1 = *(const short8*)KSB(kr, 64 + quad * 16);
      float4v s = (float4v){0.f, 0.f, 0.f, 0.f};
      s = __builtin_amdgcn_mfma_f32_16x16x32_bf16(qf0, bk0, s, 0, 0, 0);
      s = __builtin_amdgcn_mfma_f32_16x16x32_bf16(qf1, bk1, s, 0, 0, 0);
      sc[nj] = s;
    }

    // ---- positional band MFMA in two 5-frag halves + interleaved extraction ----
    const int ddminW = ddminB + toff;
    const int tmaxW = MQ - ddminW;
    float4v bc[5];
    int q2c = -1;
    short8 a0, a1;
    BANDFRAG(0, bc[0])
    BANDFRAG(1, bc[1])
    BANDFRAG(2, bc[2])
    BANDFRAG(3, bc[3])
    BANDFRAG(4, bc[4])
    __builtin_amdgcn_s_setprio(0);
    // extract njs 0..3 (uses bc[0..4])
#pragma unroll
    for (int r = 0; r < 4; ++r) {
      const int tb = 15 - quad * 4 - r;                      // in [0,15]
      const int adr = 4 * (((l15 + tb) & 15) + 16 * quad);   // source lane (same quad)
      const bool srcHi = (l15 < tb);
#pragma unroll
      for (int nj = 0; nj < 4; ++nj) {
        float mg = srcHi ? bc[nj + 1][r] : bc[nj][r];
        int p = __builtin_amdgcn_ds_bpermute(adr, __float_as_int(mg));
        float pos = __int_as_float(p);
        float v2 = (sc[nj][r] + pos) * SCL2;
        int tw = nj * 16 + l15 + tb;
        sc[nj][r] = (tw <= tmaxW) ? v2 : NEG_BIG;
      }
    }
    bc[0] = bc[4];
    __builtin_amdgcn_s_setprio(1);
    BANDFRAG(5, bc[1])
    BANDFRAG(6, bc[2])
    BANDFRAG(7, bc[3])
    BANDFRAG(8, bc[4])
    __builtin_amdgcn_s_setprio(0);
    // extract njs 4..7 (uses bc[0..4] = frags 4..8)
#pragma unroll
    for (int r = 0; r < 4; ++r) {
      const int tb = 15 - quad * 4 - r;
      const int adr = 4 * (((l15 + tb) & 15) + 16 * quad);
      const bool srcHi = (l15 < tb);
#pragma unroll
      for (int nj = 4; nj < 8; ++nj) {
        float mg = srcHi ? bc[nj - 3][r] : bc[nj - 4][r];
        int p = __builtin_amdgcn_ds_bpermute(adr, __float_as_int(mg));
        float pos = __int_as_float(p);
        float v2 = (sc[nj][r] + pos) * SCL2;
        int tw = nj * 16 + l15 + tb;
        sc[nj][r] = (tw <= tmaxW) ? v2 : NEG_BIG;
      }
    }

    // ---- V fragments group (hk0,kc0): land under softmax ----
    short8 va0 = *(const short8*)(VgT);
    short8 va1 = *(const short8*)(VgT + 512);
    short8 va2 = *(const short8*)(VgT + 1024);
    short8 va3 = *(const short8*)(VgT + 1536);

    // ---- online softmax (log2 domain); reductions on VALU via DPP ror ----
#pragma unroll
    for (int r = 0; r < 4; ++r) {
      float mx = sc[0][r];
#pragma unroll
      for (int nj = 1; nj < 8; ++nj) mx = fmaxf(mx, sc[nj][r]);
      mx = fmaxf(mx, ROR16(mx, 8));
      mx = fmaxf(mx, ROR16(mx, 4));
      mx = fmaxf(mx, ROR16(mx, 2));
      mx = fmaxf(mx, ROR16(mx, 1));
      float mnew = fmaxf(mrun[r], mx);
      float al = exp2f(mrun[r] - mnew);
      float rs = 0.f;
#pragma unroll
      for (int nj = 0; nj < 8; ++nj) {
        float pv = exp2f(sc[nj][r] - mnew);
        sc[nj][r] = pv;
        rs += pv;
      }
      rs += ROR16(rs, 8);
      rs += ROR16(rs, 4);
      rs += ROR16(rs, 2);
      rs += ROR16(rs, 1);
      lrun[r] = lrun[r] * al + rs;
      mrun[r] = mnew;
#pragma unroll
      for (int ni = 0; ni < 4; ++ni) o[ni][r] *= al;
    }

    // ---- V fragments group (hk0,kc1) ----
    short8 vb0 = *(const short8*)(VgT + 2048);
    short8 vb1 = *(const short8*)(VgT + 2560);
    short8 vb2 = *(const short8*)(VgT + 3072);
    short8 vb3 = *(const short8*)(VgT + 3584);

    // ---- P pack (fp16, per-wave Ps slice) + PV (V from registers) ----
    u16* Psw = Ps + w * 1152;   // [16][72]
    // hk = 0 pack
#pragma unroll
    for (int nj = 0; nj < 4; ++nj)
#pragma unroll
      for (int r = 0; r < 4; ++r)
        Psw[(quad * 4 + r) * 72 + nj * 16 + l15] = f2h(sc[nj][r]);
    {  // (hk=0, kc=0)
      short8 ap = *(const short8*)&Psw[l15 * 72 + quad * 8];
      __builtin_amdgcn_s_setprio(1);
      o[0] = __builtin_amdgcn_mfma_f32_16x16x32_f16(ap, va0, o[0], 0, 0, 0);
      o[1] = __builtin_amdgcn_mfma_f32_16x16x32_f16(ap, va1, o[1], 0, 0, 0);
      o[2] = __builtin_amdgcn_mfma_f32_16x16x32_f16(ap, va2, o[2], 0, 0, 0);
      o[3] = __builtin_amdgcn_mfma_f32_16x16x32_f16(ap, va3, o[3], 0, 0, 0);
      __builtin_amdgcn_s_setprio(0);
    }
    // refill for (hk=1, kc=0)
    va0 = *(const short8*)(VgT + 4096);
    va1 = *(const short8*)(VgT + 4608);
    va2 = *(const short8*)(VgT + 5120);
    va3 = *(const short8*)(VgT + 5632);
    {  // (hk=0, kc=1)
      short8 ap = *(const short8*)&Psw[l15 * 72 + 32 + quad * 8];
      __builtin_amdgcn_s_setprio(1);
      o[0] = __builtin_amdgcn_mfma_f32_16x16x32_f16(ap, vb0, o[0], 0, 0, 0);
      o[1] = __builtin_amdgcn_mfma_f32_16x16x32_f16(ap, vb1, o[1], 0, 0, 0);
      o[2] = __builtin_amdgcn_mfma_f32_16x16x32_f16(ap, vb2, o[2], 0, 0, 0);
      o[3] = __builtin_amdgcn_mfma_f32_16x16x32_f16(ap, vb3, o[3], 0, 0, 0);
      __builtin_amdgcn_s_setprio(0);
    }
    // refill for (hk=1, kc=1)
    vb0 = *(const short8*)(VgT + 6144);
    vb1 = *(const short8*)(VgT + 6656);
    vb2 = *(const short8*)(VgT + 7168);
    vb3 = *(const short8*)(VgT + 7680);
    // hk = 1 pack (same-wave LDS write->read: DS pipe is in-order per wave)
#pragma unroll
    for (int nj = 0; nj < 4; ++nj)
#pragma unroll
      for (int r = 0; r < 4; ++r)
        Psw[(quad * 4 + r) * 72 + nj * 16 + l15] = f2h(sc[4 + nj][r]);
    {  // (hk=1, kc=0)
      short8 ap = *(const short8*)&Psw[l15 * 72 + quad * 8];
      __builtin_amdgcn_s_setprio(1);
      o[0] = __builtin_amdgcn_mfma_f32_16x16x32_f16(ap, va0, o[0], 0, 0, 0);
      o[1] = __builtin_amdgcn_mfma_f32_16x16x32_f16(ap, va1, o[1], 0, 0, 0);
      o[2] = __builtin_amdgcn_mfma_f32_16x16x32_f16(ap, va2, o[2], 0, 0, 0);
      o[3] = __builtin_amdgcn_mfma_f32_16x16x32_f16(ap, va3, o[3], 0, 0, 0);
      __builtin_amdgcn_s_setprio(0);
    }
    {  // (hk=1, kc=1)
      short8 ap = *(const short8*)&Psw[l15 * 72 + 32 + quad * 8];
      __builtin_amdgcn_s_setprio(1);
      o[0] = __builtin_amdgcn_mfma_f32_16x16x32_f16(ap, vb0, o[0], 0, 0, 0);
      o[1] = __builtin_amdgcn_mfma_f32_16x16x32_f16(ap, vb1, o[1], 0, 0, 0);
      o[2] = __builtin_amdgcn_mfma_f32_16x16x32_f16(ap, vb2, o[2], 0, 0, 0);
      o[3] = __builtin_amdgcn_mfma_f32_16x16x32_f16(ap, vb3, o[3], 0, 0, 0);
      __builtin_amdgcn_s_setprio(0);
    }
    __syncthreads();   // all band/Ks reads done; next tile may overwrite
  }

#pragma unroll
  for (int r = 0; r < 4; ++r) {
    float inv = 1.0f / lrun[r];
#pragma unroll
    for (int ni = 0; ni < 4; ++ni) {
      AWV[((size_t)(b * 1024 + iw + quad * 4 + r)) * 1024 + h * 64 + ni * 16 + l15] =
          f2bf(o[ni][r] * inv);
    }
  }
}

// ---------------------------------------------------------------------------
extern "C" void kernel_launch(void* const* d_in, const int* in_sizes, int n_in,
                              void* d_out, int out_size, void* d_ws, size_t ws_size,
                              hipStream_t stream) {
  const void* input_ = d_in[0];
  const void* pose   = d_in[1];
  const void* memry  = d_in[2];
  const void* ubias  = d_in[3];
  const void* vbias  = d_in[4];
  const void* Wkv    = d_in[5];
  const void* Wq     = d_in[6];
  const void* Wp     = d_in[7];
  const void* Wout   = d_in[8];
  // d_in[9] (mask) unused: mask is j <= i + 1024, computed analytically.

  char* base = (char*)d_ws;
  size_t off = 0;
  auto carve = [&](size_t bytes) {
    void* r = base + off;
    off += (bytes + 255) & ~(size_t)255;
    return r;
  };
  int* dflag = (int*)carve(256);
  u16* Kb    = (u16*)carve((size_t)4 * 2048 * 1024 * 2);   // K  [b][t][hd] bf16
  u16* VT    = (u16*)carve((size_t)1024 * 4 * 2048 * 2);   // V4 fragment layout, fp16
  u16* QU    = (u16*)carve((size_t)4 * 1024 * 1024 * 2);
  u16* QV    = (u16*)carve((size_t)4 * 1024 * 1024 * 2);
  u16* Pb    = (u16*)carve((size_t)2048 * 1024 * 2);
  u16* AWVb  = (u16*)carve((size_t)4 * 1024 * 1024 * 2);
  u16* WkvT  = (u16*)carve((size_t)2048 * 1024 * 2);
  u16* WqT   = (u16*)carve((size_t)1024 * 1024 * 2);
  u16* WpT   = (u16*)carve((size_t)1024 * 1024 * 2);
  u16* WoutT = (u16*)carve((size_t)1024 * 1024 * 2);
  u16* inpB  = (u16*)carve((size_t)4 * 1024 * 1024 * 2);
  u16* memB  = (u16*)carve((size_t)4 * 1024 * 1024 * 2);
  u16* poseB = (u16*)carve((size_t)2048 * 1024 * 2);

  detect_dtype<<<1, 64, 0, stream>>>((const unsigned*)input_, dflag);
  // merged converts + weight transposes (one dispatch)
  prep_all<<<dim3(15360, 1, 1), 256, 0, stream>>>(
      input_, memry, pose, inpB, memB, poseB,
      Wkv, Wq, Wp, Wout, WkvT, WqT, WpT, WoutT, dflag);

  // merged projections: kv (1024 blocks) + q (256) + p (128) in one dispatch
  gemm_proj<<<dim3(1408, 1, 1), 256, 0, stream>>>(
      memB, inpB, poseB, WkvT, WqT, WpT,
      Kb, VT, QU, QV, Pb, ubias, vbias, dflag, 1024);

  // fused attention, all 16 heads in one dispatch (1024 blocks)
  attn_fused<<<dim3(16, 16, 4), 256, 0, stream>>>(QU, QV, Kb, VT, Pb, AWVb);

  // out = awv @ W_out  (M=4096, N=1024, K=1024), 64x128 tiles = 512 blocks
  gemm_out<<<dim3(8, 64, 1), 256, 0, stream>>>(AWVb, WoutT, d_out, dflag);
}

// Round 14
// 366.749 us; speedup vs baseline: 1.0650x; 1.0359x over previous
//
#include <hip/hip_runtime.h>

typedef unsigned short u16;
typedef __attribute__((ext_vector_type(8))) short short8;
typedef __attribute__((ext_vector_type(4))) float float4v;

#define SCL2 (0.125f * 1.44269504088896340736f)   // logit scale folded into log2 domain
#define NEG_BIG -1.0e8f

// 16-lane rotation on the VALU pipe (DPP row_ror) — replaces shfl_xor (DS pipe)
#define ROR16(x, N) __int_as_float(__builtin_amdgcn_mov_dpp( \
    __float_as_int(x), 0x120 + (N), 0xF, 0xF, true))

static __device__ __forceinline__ u16 f2bf(float f) {
  union { float f; unsigned u; } x; x.f = f;
  unsigned r = x.u + 0x7fffu + ((x.u >> 16) & 1u);
  return (u16)(r >> 16);
}
static __device__ __forceinline__ float bf2f(u16 b) {
  union { unsigned u; float f; } x; x.u = ((unsigned)b) << 16;
  return x.f;
}
static __device__ __forceinline__ u16 f2h(float f) {
  union { u16 u; _Float16 h; } x; x.h = (_Float16)f; return x.u;
}

// ---------------------------------------------------------------------------
// Merged prep: inline dtype detect + converts (input/memory/pose -> bf16) +
// 4 weight transposes in ONE dispatch (block-range table, block-uniform
// branches). Each block computes the f32-vs-bf16 flag locally (~40 cyc:
// per-wave ballot popcount over the first 256 words of input_, LDS combine)
// — removes the serial detect_dtype dispatch + gap. Block 0 publishes dflag
// for the downstream GEMM dispatches (which launch strictly after prep).
//   [    0, 4096): convert input  (4M)
//   [ 4096, 8192): convert memory (4M)
//   [ 8192,10240): convert pose   (2M)
//   [10240,12288): transpose Wkv  (C=2048)
//   [12288,13312): transpose Wq   (C=1024)
//   [13312,14336): transpose Wp
//   [14336,15360): transpose Wout
// ---------------------------------------------------------------------------
__global__ __launch_bounds__(256) void prep_all(
    const void* __restrict__ A0, const void* __restrict__ A1, const void* __restrict__ A2,
    u16* __restrict__ O0, u16* __restrict__ O1, u16* __restrict__ O2,
    const void* __restrict__ W0, const void* __restrict__ W1,
    const void* __restrict__ W2, const void* __restrict__ W3,
    u16* __restrict__ T0, u16* __restrict__ T1,
    u16* __restrict__ T2, u16* __restrict__ T3,
    int* __restrict__ dflag) {
  __shared__ __align__(16) u16 t[32][33];
  __shared__ int cnt4[4];
  const int bid = blockIdx.x, tid = threadIdx.x;

  // ---- inline dtype detection (identical predicate to old detect_dtype) ----
  {
    unsigned e = (((const unsigned*)A0)[tid] >> 7) & 0xFFu;
    unsigned long long bal = __ballot(e >= 100u && e <= 140u);
    if ((tid & 63) == 0) cnt4[tid >> 6] = __popcll(bal);
  }
  __syncthreads();
  const int cnt = cnt4[0] + cnt4[1] + cnt4[2] + cnt4[3];
  const int f32 = (cnt < 128) ? 1 : 0;
  if (bid == 0 && tid == 0) dflag[0] = f32;   // publish for later dispatches

  if (bid < 10240) {  // ---- converts ----
    int z = (bid < 4096) ? 0 : (bid < 8192) ? 1 : 2;
    int lb = bid - ((z == 0) ? 0 : (z == 1) ? 4096 : 8192);
    const void* in = (z == 0) ? A0 : (z == 1) ? A1 : A2;
    u16* out = (z == 0) ? O0 : (z == 1) ? O1 : O2;
    int i = (lb * 256 + tid) * 4;
    if (f32) {
      float4 v = *(const float4*)((const float*)in + i);
      u16 o[4] = {f2bf(v.x), f2bf(v.y), f2bf(v.z), f2bf(v.w)};
      *(uint2*)(out + i) = *(uint2*)o;
    } else {
      *(uint2*)(out + i) = *(const uint2*)((const u16*)in + i);
    }
    return;
  }
  // ---- transposes ----
  int z, lb;
  if (bid < 12288)      { z = 0; lb = bid - 10240; }
  else if (bid < 13312) { z = 1; lb = bid - 12288; }
  else if (bid < 14336) { z = 2; lb = bid - 13312; }
  else                  { z = 3; lb = bid - 14336; }
  const void* in = (z == 0) ? W0 : (z == 1) ? W1 : (z == 2) ? W2 : W3;
  u16* out = (z == 0) ? T0 : (z == 1) ? T1 : (z == 2) ? T2 : T3;
  const int C = (z == 0) ? 2048 : 1024;
  const int nbx = C / 32;
  const int bx = lb % nbx, by = lb / nbx;
  const int tx = tid & 31, ty = tid >> 5;            // 32x8
  int c = bx * 32 + tx;
  int rbase = by * 32;
#pragma unroll
  for (int k = 0; k < 4; ++k) {
    int r = rbase + ty + k * 8;
    size_t idx = (size_t)r * C + c;
    t[ty + k * 8][tx] = f32 ? f2bf(((const float*)in)[idx]) : ((const u16*)in)[idx];
  }
  __syncthreads();
  int r2 = rbase + tx;
#pragma unroll
  for (int k = 0; k < 4; ++k) {
    int c2 = bx * 32 + ty + k * 8;
    out[(size_t)c2 * 1024 + r2] = t[tx][ty + k * 8];
  }
}

// row pointer for A (or gathered [gmem;ginp] concat when A==nullptr)
static __device__ __forceinline__ const u16* gemm_arow(
    const u16* A, const u16* gmem, const u16* ginp,
    int lda, long aOff, long aZ, int z, int rg) {
  if (A) return A + (size_t)rg * lda + aOff + (long)z * aZ;
  int bb = rg >> 11, t = rg & 2047;
  return (t < 1024) ? (gmem + ((size_t)(bb * 1024 + t)) * 1024)
                    : (ginp + ((size_t)(bb * 1024 + t - 1024)) * 1024);
}

// ---------------------------------------------------------------------------
// Merged projection GEMM: kv + q + p in ONE dispatch (1408 blocks) — verified
// round-9/10/13. Body = round-8 loop (reg-prefetch + LDS dbuf, 1 barrier/K-step).
// K written row-major. V4 layout: V4[(((b*16+h)*16+jt)*16+f)*64+lane][i] (fp16)
// ---------------------------------------------------------------------------
__global__ __launch_bounds__(256) void gemm_proj(
    const u16* __restrict__ memB, const u16* __restrict__ inpB,
    const u16* __restrict__ poseB,
    const u16* __restrict__ WkvT, const u16* __restrict__ WqT,
    const u16* __restrict__ WpT,
    u16* __restrict__ Kb, u16* __restrict__ VT,
    u16* __restrict__ QU, u16* __restrict__ QV, u16* __restrict__ Pb,
    const void* __restrict__ ub, const void* __restrict__ vb,
    const int* __restrict__ dflag, int K)
{
  __shared__ __align__(16) u16 As[2][128][40];
  __shared__ __align__(16) u16 Bs[2][128][40];
  const int f32g = dflag[0];
  const int tid = threadIdx.x;
  const int w = tid >> 6, lane = tid & 63, quad = lane >> 4, l15 = lane & 15;
  const int wr = w >> 1, wc = w & 1;
  const int srow = tid >> 2, sc8 = (tid & 3) * 8;

  const int bid = blockIdx.x;
  int prob, bx, by;
  if (bid < 1024)      { prob = 0; bx = bid & 15; by = bid >> 4; }
  else if (bid < 1280) { int t = bid - 1024; prob = 1; bx = t & 7; by = t >> 3; }
  else                 { int t = bid - 1280; prob = 2; bx = t & 7; by = t >> 3; }
  const int m0 = by * 128, n0 = bx * 128;
  const u16* BT = (prob == 0) ? WkvT : (prob == 1) ? WqT : WpT;

  const u16 *apr0, *apr1;
  if (prob == 0) {
    apr0 = gemm_arow(nullptr, memB, inpB, 0, 0, 0, 0, m0 + srow) + sc8;
    apr1 = gemm_arow(nullptr, memB, inpB, 0, 0, 0, 0, m0 + 64 + srow) + sc8;
  } else {
    const u16* Ab = (prob == 1) ? inpB : poseB;
    apr0 = Ab + (size_t)(m0 + srow) * 1024 + sc8;
    apr1 = Ab + (size_t)(m0 + 64 + srow) * 1024 + sc8;
  }
  const u16* bpr0 = BT + (size_t)(n0 + srow) * 1024 + sc8;
  const u16* bpr1 = BT + (size_t)(n0 + 64 + srow) * 1024 + sc8;

  float4v acc[4][4];
#pragma unroll
  for (int i = 0; i < 4; ++i)
#pragma unroll
    for (int j = 0; j < 4; ++j) acc[i][j] = (float4v){0.f, 0.f, 0.f, 0.f};

  uint4 aR0 = *(const uint4*)(apr0);
  uint4 aR1 = *(const uint4*)(apr1);
  uint4 bR0 = *(const uint4*)(bpr0);
  uint4 bR1 = *(const uint4*)(bpr1);

  int p = 0;
  for (int kt = 0; kt < K; kt += 32, p ^= 1) {
    *(uint4*)&As[p][srow][sc8] = aR0;
    *(uint4*)&As[p][64 + srow][sc8] = aR1;
    *(uint4*)&Bs[p][srow][sc8] = bR0;
    *(uint4*)&Bs[p][64 + srow][sc8] = bR1;
    __syncthreads();
    if (kt + 32 < K) {
      aR0 = *(const uint4*)(apr0 + kt + 32);
      aR1 = *(const uint4*)(apr1 + kt + 32);
      bR0 = *(const uint4*)(bpr0 + kt + 32);
      bR1 = *(const uint4*)(bpr1 + kt + 32);
    }
    short8 af[4], bf[4];
#pragma unroll
    for (int mi = 0; mi < 4; ++mi)
      af[mi] = *(const short8*)&As[p][wr * 64 + mi * 16 + l15][quad * 8];
#pragma unroll
    for (int ni = 0; ni < 4; ++ni)
      bf[ni] = *(const short8*)&Bs[p][wc * 64 + ni * 16 + l15][quad * 8];
#pragma unroll
    for (int mi = 0; mi < 4; ++mi)
#pragma unroll
      for (int ni = 0; ni < 4; ++ni)
        acc[mi][ni] = __builtin_amdgcn_mfma_f32_16x16x32_bf16(af[mi], bf[ni], acc[mi][ni], 0, 0, 0);
    // single barrier per K-step: next iter writes the OTHER buffer
  }

#pragma unroll
  for (int mi = 0; mi < 4; ++mi) {
#pragma unroll
    for (int ni = 0; ni < 4; ++ni) {
      int rg0 = m0 + wr * 64 + mi * 16 + quad * 4;
      int cg = n0 + wc * 64 + ni * 16 + l15;
      if (prob == 0) {
        if (cg >= 1024) {   // V -> fragment-contiguous V4 layout (fp16)
          int d_full = cg - 1024;
          int hh = d_full >> 6, dd = d_full & 63;
          int niv = dd >> 4, lv = dd & 15;
          int bb = rg0 >> 11, t0 = rg0 & 2047;
          int jt = t0 >> 7, tp = t0 & 127;
          int f = ((tp >> 5) << 2) + niv;
          int lanev = ((tp >> 3) & 3) * 16 + lv;
          int iv = tp & 7;
          size_t Aidx = ((((size_t)(bb * 16 + hh) * 16 + jt) * 16 + f) * 64 + lanev) * 8 + iv;
          u16 h4[4] = {f2h(acc[mi][ni][0]), f2h(acc[mi][ni][1]),
                       f2h(acc[mi][ni][2]), f2h(acc[mi][ni][3])};
          *(uint2*)&VT[Aidx] = *(uint2*)h4;
        } else {
#pragma unroll
          for (int r = 0; r < 4; ++r)
            Kb[(size_t)(rg0 + r) * 1024 + cg] = f2bf(acc[mi][ni][r]);
        }
      } else if (prob == 1) {
        float uu = f32g ? ((const float*)ub)[cg] : bf2f(((const u16*)ub)[cg]);
        float vv = f32g ? ((const float*)vb)[cg] : bf2f(((const u16*)vb)[cg]);
#pragma unroll
        for (int r = 0; r < 4; ++r) {
          size_t ci = (size_t)(rg0 + r) * 1024 + cg;
          QU[ci] = f2bf(acc[mi][ni][r] + uu);
          QV[ci] = f2bf(acc[mi][ni][r] + vv);
        }
      } else {
#pragma unroll
        for (int r = 0; r < 4; ++r)
          Pb[(size_t)(rg0 + r) * 1024 + cg] = f2bf(acc[mi][ni][r]);
      }
    }
  }
}

// ---------------------------------------------------------------------------
// out projection GEMM, 64x128 tiles -> 512 blocks (2 blocks/CU).
// ---------------------------------------------------------------------------
__global__ __launch_bounds__(256) void gemm_out(
    const u16* __restrict__ A, const u16* __restrict__ BT,
    void* __restrict__ Cp, const int* __restrict__ dflag)
{
  __shared__ __align__(16) u16 As[2][64][40];
  __shared__ __align__(16) u16 Bs[2][128][40];
  const int f32g = dflag[0];
  const int tid = threadIdx.x;
  const int w = tid >> 6, lane = tid & 63, quad = lane >> 4, l15 = lane & 15;
  const int wr = w >> 1, wc = w & 1;
  const int m0 = blockIdx.y * 64, n0 = blockIdx.x * 128;
  const int srow = tid >> 2, sc8 = (tid & 3) * 8;   // srow in [0,64)

  const u16* apr0 = A + (size_t)(m0 + srow) * 1024 + sc8;
  const u16* bpr0 = BT + (size_t)(n0 + srow) * 1024 + sc8;
  const u16* bpr1 = BT + (size_t)(n0 + 64 + srow) * 1024 + sc8;

  float4v acc[2][4];
#pragma unroll
  for (int i = 0; i < 2; ++i)
#pragma unroll
    for (int j = 0; j < 4; ++j) acc[i][j] = (float4v){0.f, 0.f, 0.f, 0.f};

  uint4 aR0 = *(const uint4*)(apr0);
  uint4 bR0 = *(const uint4*)(bpr0);
  uint4 bR1 = *(const uint4*)(bpr1);

  int p = 0;
  for (int kt = 0; kt < 1024; kt += 32, p ^= 1) {
    *(uint4*)&As[p][srow][sc8] = aR0;
    *(uint4*)&Bs[p][srow][sc8] = bR0;
    *(uint4*)&Bs[p][64 + srow][sc8] = bR1;
    __syncthreads();
    if (kt + 32 < 1024) {
      aR0 = *(const uint4*)(apr0 + kt + 32);
      bR0 = *(const uint4*)(bpr0 + kt + 32);
      bR1 = *(const uint4*)(bpr1 + kt + 32);
    }
    short8 af[2], bf[4];
#pragma unroll
    for (int mi = 0; mi < 2; ++mi)
      af[mi] = *(const short8*)&As[p][wr * 32 + mi * 16 + l15][quad * 8];
#pragma unroll
    for (int ni = 0; ni < 4; ++ni)
      bf[ni] = *(const short8*)&Bs[p][wc * 64 + ni * 16 + l15][quad * 8];
#pragma unroll
    for (int mi = 0; mi < 2; ++mi)
#pragma unroll
      for (int ni = 0; ni < 4; ++ni)
        acc[mi][ni] = __builtin_amdgcn_mfma_f32_16x16x32_bf16(af[mi], bf[ni], acc[mi][ni], 0, 0, 0);
    // single barrier per K-step (dbuf)
  }

#pragma unroll
  for (int mi = 0; mi < 2; ++mi) {
#pragma unroll
    for (int ni = 0; ni < 4; ++ni) {
      int rg0 = m0 + wr * 32 + mi * 16 + quad * 4;
      int cg = n0 + wc * 64 + ni * 16 + l15;
#pragma unroll
      for (int r = 0; r < 4; ++r) {
        size_t ci = (size_t)(rg0 + r) * 1024 + cg;
        float va = acc[mi][ni][r];
        if (f32g) ((float*)Cp)[ci] = va;
        else      ((u16*)Cp)[ci] = f2bf(va);
      }
    }
  }
}

// band-element load: resolves rel-shift row for column dd, zero at jp==0
#define BLD(itc) ({ \
  int dd_ = ddmN + (itc) * 32 + trow; \
  int q2_ = (dd_ >= 2049) + (dd_ >= 4098); \
  int jp_ = dd_ - 2049 * q2_; \
  uint4 pv_ = *(const uint4*)(PbH + (size_t)((jp_ > 0) ? jp_ - 1 : 0) * 1024); \
  uint4 z4_ = {0u, 0u, 0u, 0u}; \
  (jp_ == 0) ? z4_ : pv_; })

// Ks packed [128 rows][64 d] bf16, XOR-swizzled 16B slots (bank-balance):
// byte addr = row*128 + (col_byte ^ ((row&7)<<4)); all accesses 16B granule.
#define KSB(row, cb) ((char*)Ks + (size_t)(row) * 128 + ((cb) ^ (((row) & 7) << 4)))
// qvs packed [66 rows][64 d] bf16, same swizzle (verified r11/r13)
#define QSB(row, cb) ((char*)qvs + (size_t)(row) * 128 + ((cb) ^ (((row) & 7) << 4)))

// band fragment: rows (q+v) x band cols, with rel-shift threshold crossing merge
#define BANDFRAG(fc, dst) { \
      int dds = ddminW + (fc) * 16; \
      int qlo = (dds >= 2049) + (dds >= 4098); \
      int qhi = (dds + 15 >= 2049) + (dds + 15 >= 4098); \
      if (qlo != q2c) { \
        const int qr_ = 16 * w + l15 + qlo; \
        a0 = *(const short8*)QSB(qr_, quad * 16); \
        a1 = *(const short8*)QSB(qr_, 64 + quad * 16); \
        q2c = qlo; \
      } \
      const u16* br = &band[(toff + (fc) * 16 + l15) * 72]; \
      short8 b0 = *(const short8*)(br + quad * 8); \
      short8 b1 = *(const short8*)(br + 32 + quad * 8); \
      float4v c = (float4v){0.f, 0.f, 0.f, 0.f}; \
      c = __builtin_amdgcn_mfma_f32_16x16x32_bf16(a0, b0, c, 0, 0, 0); \
      c = __builtin_amdgcn_mfma_f32_16x16x32_bf16(a1, b1, c, 0, 0, 0); \
      if (qhi != qlo) { \
        const int qr2_ = 16 * w + l15 + qhi; \
        short8 e0 = *(const short8*)QSB(qr2_, quad * 16); \
        short8 e1 = *(const short8*)QSB(qr2_, 64 + quad * 16); \
        float4v c2 = (float4v){0.f, 0.f, 0.f, 0.f}; \
        c2 = __builtin_amdgcn_mfma_f32_16x16x32_bf16(e0, b0, c2, 0, 0, 0); \
        c2 = __builtin_amdgcn_mfma_f32_16x16x32_bf16(e1, b1, c2, 0, 0, 0); \
        int colX = ((qlo == 0) ? 2049 : 4098) - dds; \
        bool useHi = (l15 >= colX); \
        for (int rr = 0; rr < 4; ++rr) c[rr] = useHi ? c2[rr] : c[rr]; \
      } \
      dst = c; }

// ---------------------------------------------------------------------------
// Fused flash attention — round-13 verified configuration (177.5us):
// r6 structure + qvs [66][64] XOR-swizzle. Unchanged.
// ---------------------------------------------------------------------------
__global__ __launch_bounds__(256, 2) void attn_fused(
    const u16* __restrict__ QU, const u16* __restrict__ QV,
    const u16* __restrict__ Kb, const u16* __restrict__ VT,
    const u16* __restrict__ Pb, u16* __restrict__ AWV)
{
  __shared__ __align__(16) u16 band[192 * 72];   // p-band
  __shared__ __align__(16) u16 Ks[128 * 64];     // K tile packed [j][d] bf16, swizzled
  __shared__ __align__(16) u16 qvs[66 * 64];     // (q+v) rows packed bf16, swizzled
  __shared__ __align__(16) u16 Ps[4 * 16 * 72];  // per-wave P slices (fp16)
  const int b = blockIdx.z, h = blockIdx.y;
  const int i0 = (15 - blockIdx.x) * 64;         // big blocks first
  const int tid = threadIdx.x, w = tid >> 6, lane = tid & 63;
  const int quad = lane >> 4, l15 = lane & 15;
  const int iw = i0 + w * 16;
  const int m0 = b * 1024 + i0;
  const int MQ = 5120 - 1024 * b;                // dd <= MQ <=> unmasked

  // content-Q fragment (q+u)
  const size_t qb = ((size_t)(b * 1024 + iw + l15)) * 1024 + h * 64 + quad * 8;
  short8 qf0 = *(const short8*)(QU + qb);
  short8 qf1 = *(const short8*)(QU + qb + 32);

  // stage qv rows once per block (66 rows x 64 d, swizzled)
#pragma unroll
  for (int it = 0; it < 3; ++it) {
    int slot = it * 256 + tid;
    if (slot < 528) {
      int row = slot >> 3, d8q = (slot & 7) * 8;
      int gr = m0 + row; if (gr > 4095) gr = 4095;   // tail rows never used in-mask
      *(uint4*)QSB(row, (slot & 7) * 16) =
          *(const uint4*)(QV + (size_t)gr * 1024 + h * 64 + d8q);
    }
  }

  float4v o[4];
#pragma unroll
  for (int ni = 0; ni < 4; ++ni) o[ni] = (float4v){0.f, 0.f, 0.f, 0.f};
  float mrun[4] = {NEG_BIG, NEG_BIG, NEG_BIG, NEG_BIG};
  float lrun[4] = {0.f, 0.f, 0.f, 0.f};

  const int toff = 48 - 16 * w;                  // wave band offset in block band
  const int nT = (i0 + 1088 + 127) / 128;

  // fixed per-thread staging slots + hoisted base pointers
  const int trow = tid >> 3, d8 = (tid & 7) * 8;   // band/Ks
  const u16* PbH = Pb + h * 64 + d8;
  const u16* KbH = Kb + ((size_t)(b * 2048 + trow)) * 1024 + h * 64 + d8;
  // V4 fragment base: per (b,h) chunk of 131072 halves, +lane*8
  const u16* Vg = VT + (size_t)(b * 16 + h) * 131072 + (size_t)lane * 8;
  const int ddm0 = 4096 - m0 - 63 + trow;          // dd at (j0=0, it=0)

  // ---- prologue: prefetch tile 0 into named registers ----
  int ddmN = ddm0 - trow;   // BLD adds trow back
  uint4 bRa = BLD(0), bRb = BLD(1), bRc = BLD(2), bRd = BLD(3), bRe = BLD(4), bRf = BLD(5);
  uint4 kRa = *(const uint4*)(KbH);
  uint4 kRb = *(const uint4*)(KbH + 32 * 1024);
  uint4 kRc = *(const uint4*)(KbH + 64 * 1024);
  uint4 kRd = *(const uint4*)(KbH + 96 * 1024);

  for (int jt = 0; jt < nT; ++jt) {
    const int j0 = jt * 128;
    const int ddminB = j0 + 4096 - (m0 + 63);
    const u16* VgT = Vg + (size_t)jt * 8192;

    // ---- LDS write phase (from prefetched registers) ----
    *(uint4*)&band[(0 * 32 + trow) * 72 + d8] = bRa;
    *(uint4*)&band[(1 * 32 + trow) * 72 + d8] = bRb;
    *(uint4*)&band[(2 * 32 + trow) * 72 + d8] = bRc;
    *(uint4*)&band[(3 * 32 + trow) * 72 + d8] = bRd;
    *(uint4*)&band[(4 * 32 + trow) * 72 + d8] = bRe;
    *(uint4*)&band[(5 * 32 + trow) * 72 + d8] = bRf;
    *(uint4*)KSB(0 * 32 + trow, (tid & 7) * 16) = kRa;
    *(uint4*)KSB(1 * 32 + trow, (tid & 7) * 16) = kRb;
    *(uint4*)KSB(2 * 32 + trow, (tid & 7) * 16) = kRc;
    *(uint4*)KSB(3 * 32 + trow, (tid & 7) * 16) = kRd;
    __syncthreads();

    // ---- issue next tile's loads (drain overlaps this tile's compute) ----
    if (jt + 1 < nT) {
      const int j0n = j0 + 128;
      ddmN = j0n + 4096 - m0 - 63;
      bRa = BLD(0); bRb = BLD(1); bRc = BLD(2);
      bRd = BLD(3); bRe = BLD(4); bRf = BLD(5);
      const u16* kp = KbH + (size_t)j0n * 1024;
      kRa = *(const uint4*)(kp);
      kRb = *(const uint4*)(kp + 32 * 1024);
      kRc = *(const uint4*)(kp + 64 * 1024);
      kRd = *(const uint4*)(kp + 96 * 1024);
    }

    // ---- content QK^T ----
    float4v sc[8];
    __builtin_amdgcn_s_setprio(1);
#pragma unroll
    for (int nj = 0; nj < 8; ++nj) {
      const int kr = nj * 16 + l15;
      short8 bk0 = *(const short8*)KSB(kr, quad * 16);
      short8 bk1 = *(const short8*)KSB(kr, 64 + quad * 16);
      float4v s = (float4v){0.f, 0.f, 0.f, 0.f};
      s = __builtin_amdgcn_mfma_f32_16x16x32_bf16(qf0, bk0, s, 0, 0, 0);
      s = __builtin_amdgcn_mfma_f32_16x16x32_bf16(qf1, bk1, s, 0, 0, 0);
      sc[nj] = s;
    }

    // ---- positional band MFMA in two 5-frag halves + interleaved extraction ----
    const int ddminW = ddminB + toff;
    const int tmaxW = MQ - ddminW;
    float4v bc[5];
    int q2c = -1;
    short8 a0, a1;
    BANDFRAG(0, bc[0])
    BANDFRAG(1, bc[1])
    BANDFRAG(2, bc[2])
    BANDFRAG(3, bc[3])
    BANDFRAG(4, bc[4])
    __builtin_amdgcn_s_setprio(0);
    // extract njs 0..3 (uses bc[0..4])
#pragma unroll
    for (int r = 0; r < 4; ++r) {
      const int tb = 15 - quad * 4 - r;                      // in [0,15]
      const int adr = 4 * (((l15 + tb) & 15) + 16 * quad);   // source lane (same quad)
      const bool srcHi = (l15 < tb);
#pragma unroll
      for (int nj = 0; nj < 4; ++nj) {
        float mg = srcHi ? bc[nj + 1][r] : bc[nj][r];
        int p = __builtin_amdgcn_ds_bpermute(adr, __float_as_int(mg));
        float pos = __int_as_float(p);
        float v2 = (sc[nj][r] + pos) * SCL2;
        int tw = nj * 16 + l15 + tb;
        sc[nj][r] = (tw <= tmaxW) ? v2 : NEG_BIG;
      }
    }
    bc[0] = bc[4];
    __builtin_amdgcn_s_setprio(1);
    BANDFRAG(5, bc[1])
    BANDFRAG(6, bc[2])
    BANDFRAG(7, bc[3])
    BANDFRAG(8, bc[4])
    __builtin_amdgcn_s_setprio(0);
    // extract njs 4..7 (uses bc[0..4] = frags 4..8)
#pragma unroll
    for (int r = 0; r < 4; ++r) {
      const int tb = 15 - quad * 4 - r;
      const int adr = 4 * (((l15 + tb) & 15) + 16 * quad);
      const bool srcHi = (l15 < tb);
#pragma unroll
      for (int nj = 4; nj < 8; ++nj) {
        float mg = srcHi ? bc[nj - 3][r] : bc[nj - 4][r];
        int p = __builtin_amdgcn_ds_bpermute(adr, __float_as_int(mg));
        float pos = __int_as_float(p);
        float v2 = (sc[nj][r] + pos) * SCL2;
        int tw = nj * 16 + l15 + tb;
        sc[nj][r] = (tw <= tmaxW) ? v2 : NEG_BIG;
      }
    }

    // ---- V fragments group (hk0,kc0): land under softmax ----
    short8 va0 = *(const short8*)(VgT);
    short8 va1 = *(const short8*)(VgT + 512);
    short8 va2 = *(const short8*)(VgT + 1024);
    short8 va3 = *(const short8*)(VgT + 1536);

    // ---- online softmax (log2 domain); reductions on VALU via DPP ror ----
#pragma unroll
    for (int r = 0; r < 4; ++r) {
      float mx = sc[0][r];
#pragma unroll
      for (int nj = 1; nj < 8; ++nj) mx = fmaxf(mx, sc[nj][r]);
      mx = fmaxf(mx, ROR16(mx, 8));
      mx = fmaxf(mx, ROR16(mx, 4));
      mx = fmaxf(mx, ROR16(mx, 2));
      mx = fmaxf(mx, ROR16(mx, 1));
      float mnew = fmaxf(mrun[r], mx);
      float al = exp2f(mrun[r] - mnew);
      float rs = 0.f;
#pragma unroll
      for (int nj = 0; nj < 8; ++nj) {
        float pv = exp2f(sc[nj][r] - mnew);
        sc[nj][r] = pv;
        rs += pv;
      }
      rs += ROR16(rs, 8);
      rs += ROR16(rs, 4);
      rs += ROR16(rs, 2);
      rs += ROR16(rs, 1);
      lrun[r] = lrun[r] * al + rs;
      mrun[r] = mnew;
#pragma unroll
      for (int ni = 0; ni < 4; ++ni) o[ni][r] *= al;
    }

    // ---- V fragments group (hk0,kc1) ----
    short8 vb0 = *(const short8*)(VgT + 2048);
    short8 vb1 = *(const short8*)(VgT + 2560);
    short8 vb2 = *(const short8*)(VgT + 3072);
    short8 vb3 = *(const short8*)(VgT + 3584);

    // ---- P pack (fp16, per-wave Ps slice) + PV (V from registers) ----
    u16* Psw = Ps + w * 1152;   // [16][72]
    // hk = 0 pack
#pragma unroll
    for (int nj = 0; nj < 4; ++nj)
#pragma unroll
      for (int r = 0; r < 4; ++r)
        Psw[(quad * 4 + r) * 72 + nj * 16 + l15] = f2h(sc[nj][r]);
    {  // (hk=0, kc=0)
      short8 ap = *(const short8*)&Psw[l15 * 72 + quad * 8];
      __builtin_amdgcn_s_setprio(1);
      o[0] = __builtin_amdgcn_mfma_f32_16x16x32_f16(ap, va0, o[0], 0, 0, 0);
      o[1] = __builtin_amdgcn_mfma_f32_16x16x32_f16(ap, va1, o[1], 0, 0, 0);
      o[2] = __builtin_amdgcn_mfma_f32_16x16x32_f16(ap, va2, o[2], 0, 0, 0);
      o[3] = __builtin_amdgcn_mfma_f32_16x16x32_f16(ap, va3, o[3], 0, 0, 0);
      __builtin_amdgcn_s_setprio(0);
    }
    // refill for (hk=1, kc=0)
    va0 = *(const short8*)(VgT + 4096);
    va1 = *(const short8*)(VgT + 4608);
    va2 = *(const short8*)(VgT + 5120);
    va3 = *(const short8*)(VgT + 5632);
    {  // (hk=0, kc=1)
      short8 ap = *(const short8*)&Psw[l15 * 72 + 32 + quad * 8];
      __builtin_amdgcn_s_setprio(1);
      o[0] = __builtin_amdgcn_mfma_f32_16x16x32_f16(ap, vb0, o[0], 0, 0, 0);
      o[1] = __builtin_amdgcn_mfma_f32_16x16x32_f16(ap, vb1, o[1], 0, 0, 0);
      o[2] = __builtin_amdgcn_mfma_f32_16x16x32_f16(ap, vb2, o[2], 0, 0, 0);
      o[3] = __builtin_amdgcn_mfma_f32_16x16x32_f16(ap, vb3, o[3], 0, 0, 0);
      __builtin_amdgcn_s_setprio(0);
    }
    // refill for (hk=1, kc=1)
    vb0 = *(const short8*)(VgT + 6144);
    vb1 = *(const short8*)(VgT + 6656);
    vb2 = *(const short8*)(VgT + 7168);
    vb3 = *(const short8*)(VgT + 7680);
    // hk = 1 pack (same-wave LDS write->read: DS pipe is in-order per wave)
#pragma unroll
    for (int nj = 0; nj < 4; ++nj)
#pragma unroll
      for (int r = 0; r < 4; ++r)
        Psw[(quad * 4 + r) * 72 + nj * 16 + l15] = f2h(sc[4 + nj][r]);
    {  // (hk=1, kc=0)
      short8 ap = *(const short8*)&Psw[l15 * 72 + quad * 8];
      __builtin_amdgcn_s_setprio(1);
      o[0] = __builtin_amdgcn_mfma_f32_16x16x32_f16(ap, va0, o[0], 0, 0, 0);
      o[1] = __builtin_amdgcn_mfma_f32_16x16x32_f16(ap, va1, o[1], 0, 0, 0);
      o[2] = __builtin_amdgcn_mfma_f32_16x16x32_f16(ap, va2, o[2], 0, 0, 0);
      o[3] = __builtin_amdgcn_mfma_f32_16x16x32_f16(ap, va3, o[3], 0, 0, 0);
      __builtin_amdgcn_s_setprio(0);
    }
    {  // (hk=1, kc=1)
      short8 ap = *(const short8*)&Psw[l15 * 72 + 32 + quad * 8];
      __builtin_amdgcn_s_setprio(1);
      o[0] = __builtin_amdgcn_mfma_f32_16x16x32_f16(ap, vb0, o[0], 0, 0, 0);
      o[1] = __builtin_amdgcn_mfma_f32_16x16x32_f16(ap, vb1, o[1], 0, 0, 0);
      o[2] = __builtin_amdgcn_mfma_f32_16x16x32_f16(ap, vb2, o[2], 0, 0, 0);
      o[3] = __builtin_amdgcn_mfma_f32_16x16x32_f16(ap, vb3, o[3], 0, 0, 0);
      __builtin_amdgcn_s_setprio(0);
    }
    __syncthreads();   // all band/Ks reads done; next tile may overwrite
  }

#pragma unroll
  for (int r = 0; r < 4; ++r) {
    float inv = 1.0f / lrun[r];
#pragma unroll
    for (int ni = 0; ni < 4; ++ni) {
      AWV[((size_t)(b * 1024 + iw + quad * 4 + r)) * 1024 + h * 64 + ni * 16 + l15] =
          f2bf(o[ni][r] * inv);
    }
  }
}

// ---------------------------------------------------------------------------
extern "C" void kernel_launch(void* const* d_in, const int* in_sizes, int n_in,
                              void* d_out, int out_size, void* d_ws, size_t ws_size,
                              hipStream_t stream) {
  const void* input_ = d_in[0];
  const void* pose   = d_in[1];
  const void* memry  = d_in[2];
  const void* ubias  = d_in[3];
  const void* vbias  = d_in[4];
  const void* Wkv    = d_in[5];
  const void* Wq     = d_in[6];
  const void* Wp     = d_in[7];
  const void* Wout   = d_in[8];
  // d_in[9] (mask) unused: mask is j <= i + 1024, computed analytically.

  char* base = (char*)d_ws;
  size_t off = 0;
  auto carve = [&](size_t bytes) {
    void* r = base + off;
    off += (bytes + 255) & ~(size_t)255;
    return r;
  };
  int* dflag = (int*)carve(256);
  u16* Kb    = (u16*)carve((size_t)4 * 2048 * 1024 * 2);   // K  [b][t][hd] bf16
  u16* VT    = (u16*)carve((size_t)1024 * 4 * 2048 * 2);   // V4 fragment layout, fp16
  u16* QU    = (u16*)carve((size_t)4 * 1024 * 1024 * 2);
  u16* QV    = (u16*)carve((size_t)4 * 1024 * 1024 * 2);
  u16* Pb    = (u16*)carve((size_t)2048 * 1024 * 2);
  u16* AWVb  = (u16*)carve((size_t)4 * 1024 * 1024 * 2);
  u16* WkvT  = (u16*)carve((size_t)2048 * 1024 * 2);
  u16* WqT   = (u16*)carve((size_t)1024 * 1024 * 2);
  u16* WpT   = (u16*)carve((size_t)1024 * 1024 * 2);
  u16* WoutT = (u16*)carve((size_t)1024 * 1024 * 2);
  u16* inpB  = (u16*)carve((size_t)4 * 1024 * 1024 * 2);
  u16* memB  = (u16*)carve((size_t)4 * 1024 * 1024 * 2);
  u16* poseB = (u16*)carve((size_t)2048 * 1024 * 2);

  // merged inline-detect + converts + weight transposes (one dispatch;
  // block 0 publishes dflag for the downstream GEMM dispatches)
  prep_all<<<dim3(15360, 1, 1), 256, 0, stream>>>(
      input_, memry, pose, inpB, memB, poseB,
      Wkv, Wq, Wp, Wout, WkvT, WqT, WpT, WoutT, dflag);

  // merged projections: kv (1024 blocks) + q (256) + p (128) in one dispatch
  gemm_proj<<<dim3(1408, 1, 1), 256, 0, stream>>>(
      memB, inpB, poseB, WkvT, WqT, WpT,
      Kb, VT, QU, QV, Pb, ubias, vbias, dflag, 1024);

  // fused attention, all 16 heads in one dispatch (1024 blocks)
  attn_fused<<<dim3(16, 16, 4), 256, 0, stream>>>(QU, QV, Kb, VT, Pb, AWVb);

  // out = awv @ W_out  (M=4096, N=1024, K=1024), 64x128 tiles = 512 blocks
  gemm_out<<<dim3(8, 64, 1), 256, 0, stream>>>(AWVb, WoutT, d_out, dflag);
}